// Round 3
// baseline (267.897 us; speedup 1.0000x reference)
//
#include <hip/hip_runtime.h>
#include <math.h>

// Problem constants
#define NB 4
#define TT 256
#define DMODEL 1024
#define NE 16
#define DLQ 64
#define NH 4
#define HD 16
#define SEQL 17
#define NTOK 1024   // NB*TT

// Workspace layout (float offsets). Regions overlay in time:
//   A'/B' (bf16 GEMM operands) die after k_ef_mfma; EO/WUPT/CNT/LIST/LW
//   overlay them and are written only afterwards. Max offset identical to
//   the round-1 proven footprint (~16.9 MB).
static constexpr size_t WS_EF    = 0;          // 1024x1024 fp32 ef
static constexpr size_t WS_A     = 1048576;    // A' bf16 1024x3072 (dead after mfma)
static constexpr size_t WS_B     = 2621440;    // B' bf16 1024x3072 (dead after mfma)
static constexpr size_t WS_EO    = 1048576;    // 2048x1024 fp32 eo (overlays A' + low B')
static constexpr size_t WS_WUPT  = 3145728;    // w_up^T bf16 [16][1024][64] (overlays high B')
static constexpr size_t WS_CNT   = 3670016;    // 16 int expert counters
static constexpr size_t WS_LIST  = 3670032;    // 16x1024 int packed (tok*2+slot)
static constexpr size_t WS_LW    = 3686416;    // 16x1024 float weights
static constexpr size_t WS_XPART = 4194304;    // 32x1024 batch partials (early)
static constexpr size_t WS_PR    = 4194304;    // 1024x16 probs (late, overlays XPART)
static constexpr size_t WS_TW    = 4210688;    // 1024x2 top-k weights
static constexpr size_t WS_TI    = 4212736;    // 1024x2 top-k indices (int)
static constexpr size_t WS_GCTX  = 4227072;    // 4x64
static constexpr size_t WS_GB    = 4227328;    // 4x16

typedef __attribute__((ext_vector_type(8))) short short8;
typedef __attribute__((ext_vector_type(4))) float f32x4;

__device__ __forceinline__ float gelu_exact(float x) {
    return 0.5f * x * (1.0f + erff(x * 0.70710678118654752f));
}

__device__ __forceinline__ unsigned short f2bf(float f) {
    unsigned int u = __float_as_uint(f);
    unsigned int r = (u + 0x7fffu + ((u >> 16) & 1u)) >> 16;
    return (unsigned short)r;
}
__device__ __forceinline__ float bf2f(unsigned short h) {
    return __uint_as_float(((unsigned int)h) << 16);
}

#define WSUM(v) { v += __shfl_xor(v,1); v += __shfl_xor(v,2); v += __shfl_xor(v,4); \
                  v += __shfl_xor(v,8); v += __shfl_xor(v,16); v += __shfl_xor(v,32); }
#define GSUM16(v) { v += __shfl_xor(v,1); v += __shfl_xor(v,2); v += __shfl_xor(v,4); \
                    v += __shfl_xor(v,8); }

// K0: build split-bf16 operands. A' row = [xh | xl | xh], B' row = [wh | wh | wl]
__global__ __launch_bounds__(256) void k_prep(const float* __restrict__ x,
                                              const float* __restrict__ wdn,
                                              float* __restrict__ ws) {
    int row = blockIdx.x, t = threadIdx.x;
    const float* src = blockIdx.y ? wdn : x;
    unsigned short* dst = (unsigned short*)(ws + (blockIdx.y ? WS_B : WS_A)) + (size_t)row * 3072;
    float4 v = *(const float4*)(src + (size_t)row * DMODEL + t * 4);
    ushort4 hi4, lo4;
    hi4.x = f2bf(v.x); lo4.x = f2bf(v.x - bf2f(hi4.x));
    hi4.y = f2bf(v.y); lo4.y = f2bf(v.y - bf2f(hi4.y));
    hi4.z = f2bf(v.z); lo4.z = f2bf(v.z - bf2f(hi4.z));
    hi4.w = f2bf(v.w); lo4.w = f2bf(v.w - bf2f(hi4.w));
    if (blockIdx.y == 0) {
        *(ushort4*)(dst + t * 4)        = hi4;
        *(ushort4*)(dst + 1024 + t * 4) = lo4;
        *(ushort4*)(dst + 2048 + t * 4) = hi4;
    } else {
        *(ushort4*)(dst + t * 4)        = hi4;
        *(ushort4*)(dst + 1024 + t * 4) = hi4;
        *(ushort4*)(dst + 2048 + t * 4) = lo4;
    }
}

// K1a: per-(batch, slice) column sums of x
__global__ __launch_bounds__(256) void k_batch_partial(const float* __restrict__ x,
                                                       float* __restrict__ ws) {
    int b = blockIdx.x >> 3;
    int g = blockIdx.x & 7;
    int tid = threadIdx.x;
    const float* xp = x + (size_t)b * TT * DMODEL + (size_t)g * 32 * DMODEL + tid * 4;
    float4 acc = {0.f, 0.f, 0.f, 0.f};
#pragma unroll 4
    for (int t = 0; t < 32; ++t) {
        float4 v = *(const float4*)(xp + (size_t)t * DMODEL);
        acc.x += v.x; acc.y += v.y; acc.z += v.z; acc.w += v.w;
    }
    *(float4*)(ws + WS_XPART + (size_t)blockIdx.x * DMODEL + tid * 4) = acc;
}

// K1b: per batch: xmean -> gctx -> gelu MLP -> gb
__global__ __launch_bounds__(256) void k_global_ctx(const float* __restrict__ gp_w,
                                                    const float* __restrict__ gp_b,
                                                    const float* __restrict__ g1_w,
                                                    const float* __restrict__ g1_b,
                                                    const float* __restrict__ g2_w,
                                                    const float* __restrict__ g2_b,
                                                    float* __restrict__ ws) {
    int b = blockIdx.x, tid = threadIdx.x;
    __shared__ float xm[DMODEL];
    __shared__ float gc[DLQ];
    __shared__ float gb1[128];
    float4 a = {0.f, 0.f, 0.f, 0.f};
#pragma unroll
    for (int g = 0; g < 8; ++g) {
        float4 v = *(const float4*)(ws + WS_XPART + (size_t)(b * 8 + g) * DMODEL + tid * 4);
        a.x += v.x; a.y += v.y; a.z += v.z; a.w += v.w;
    }
    const float inv_t = 1.0f / (float)TT;
    xm[tid * 4 + 0] = a.x * inv_t;
    xm[tid * 4 + 1] = a.y * inv_t;
    xm[tid * 4 + 2] = a.z * inv_t;
    xm[tid * 4 + 3] = a.w * inv_t;
    __syncthreads();
    if (tid < DLQ) {
        const float* wr = gp_w + (size_t)tid * DMODEL;
        float s = 0.f;
        for (int j = 0; j < DMODEL; j += 4) {
            float4 w4 = *(const float4*)(wr + j);
            float4 x4 = *(const float4*)&xm[j];
            s += w4.x * x4.x + w4.y * x4.y + w4.z * x4.z + w4.w * x4.w;
        }
        float v = s + gp_b[tid];
        gc[tid] = v;
        ws[WS_GCTX + b * DLQ + tid] = v;
    }
    __syncthreads();
    if (tid < 128) {
        const float* wr = g1_w + (size_t)tid * DLQ;
        float s = 0.f;
        for (int j = 0; j < DLQ; j += 4) {
            float4 w4 = *(const float4*)(wr + j);
            float4 x4 = *(const float4*)&gc[j];
            s += w4.x * x4.x + w4.y * x4.y + w4.z * x4.z + w4.w * x4.w;
        }
        gb1[tid] = gelu_exact(s + g1_b[tid]);
    }
    __syncthreads();
    if (tid < NE) {
        const float* wr = g2_w + (size_t)tid * 128;
        float s = 0.f;
        for (int j = 0; j < 128; ++j) s += wr[j] * gb1[j];
        ws[WS_GB + b * NE + tid] = s + g2_b[tid];
    }
}

// K2: ef = A' . B'^T via bf16 MFMA, K=3072, 64x64 tile (unchanged this round).
__global__ __launch_bounds__(256) void k_ef_mfma(float* __restrict__ ws) {
    __shared__ __attribute__((aligned(16))) unsigned short As[64 * 64];
    __shared__ __attribute__((aligned(16))) unsigned short Bs[64 * 64];
    const unsigned short* A = (const unsigned short*)(ws + WS_A);
    const unsigned short* B = (const unsigned short*)(ws + WS_B);
    int tid = threadIdx.x;
    int m0 = blockIdx.x * 64;
    int n0 = blockIdx.y * 64;
    int lr = tid >> 3;
    int lc = (tid & 7) * 8;
    const unsigned short* gA = A + (size_t)(n0 + lr) * 3072 + lc;
    const unsigned short* gB = B + (size_t)(m0 + lr) * 3072 + lc;

    int w = tid >> 6, l = tid & 63;
    int wn = (w >> 1) * 32, wm = (w & 1) * 32;
    int fr = l & 15;
    int fk = (l >> 4) * 8;
    f32x4 acc00 = {0.f, 0.f, 0.f, 0.f}, acc01 = acc00, acc10 = acc00, acc11 = acc00;

    for (int kt = 0; kt < 48; ++kt) {
        __builtin_amdgcn_global_load_lds(
            (const __attribute__((address_space(1))) void*)(gA),
            (__attribute__((address_space(3))) void*)((char*)As + tid * 16), 16, 0, 0);
        __builtin_amdgcn_global_load_lds(
            (const __attribute__((address_space(1))) void*)(gA + 32 * 3072),
            (__attribute__((address_space(3))) void*)((char*)As + 4096 + tid * 16), 16, 0, 0);
        __builtin_amdgcn_global_load_lds(
            (const __attribute__((address_space(1))) void*)(gB),
            (__attribute__((address_space(3))) void*)((char*)Bs + tid * 16), 16, 0, 0);
        __builtin_amdgcn_global_load_lds(
            (const __attribute__((address_space(1))) void*)(gB + 32 * 3072),
            (__attribute__((address_space(3))) void*)((char*)Bs + 4096 + tid * 16), 16, 0, 0);
        gA += 64; gB += 64;
        __syncthreads();
#pragma unroll
        for (int ks = 0; ks < 64; ks += 32) {
            short8 a0 = *(const short8*)&As[(wn + fr) * 64 + fk + ks];
            short8 a1 = *(const short8*)&As[(wn + 16 + fr) * 64 + fk + ks];
            short8 b0 = *(const short8*)&Bs[(wm + fr) * 64 + fk + ks];
            short8 b1 = *(const short8*)&Bs[(wm + 16 + fr) * 64 + fk + ks];
            acc00 = __builtin_amdgcn_mfma_f32_16x16x32_bf16(a0, b0, acc00, 0, 0, 0);
            acc01 = __builtin_amdgcn_mfma_f32_16x16x32_bf16(a0, b1, acc01, 0, 0, 0);
            acc10 = __builtin_amdgcn_mfma_f32_16x16x32_bf16(a1, b0, acc10, 0, 0, 0);
            acc11 = __builtin_amdgcn_mfma_f32_16x16x32_bf16(a1, b1, acc11, 0, 0, 0);
        }
        __syncthreads();
    }
    int cr = (l >> 4) * 4, cc = l & 15;
    float* efb = ws + WS_EF;
#pragma unroll
    for (int r = 0; r < 4; ++r) {
        efb[(size_t)(n0 + wn + cr + r) * DMODEL + (m0 + wm + cc)]           = acc00[r];
        efb[(size_t)(n0 + wn + cr + r) * DMODEL + (m0 + wm + 16 + cc)]      = acc01[r];
        efb[(size_t)(n0 + wn + 16 + cr + r) * DMODEL + (m0 + wm + cc)]      = acc10[r];
        efb[(size_t)(n0 + wn + 16 + cr + r) * DMODEL + (m0 + wm + 16 + cc)] = acc11[r];
    }
}

// K2b: transpose w_up -> bf16 w_up^T [e][col][j]; also zero expert counters.
__global__ __launch_bounds__(256) void k_prep_wup(const float* __restrict__ w_up,
                                                  float* __restrict__ ws) {
    int e = blockIdx.x, ct = blockIdx.y, tid = threadIdx.x;
    __shared__ float tile[64][65];
#pragma unroll
    for (int jj = 0; jj < 16; ++jj) {
        int j = jj * 4 + (tid >> 6);
        tile[j][tid & 63] = w_up[((size_t)e * DLQ + j) * DMODEL + ct * 64 + (tid & 63)];
    }
    if (e == 0 && ct == 0 && tid < 16) ((int*)(ws + WS_CNT))[tid] = 0;
    __syncthreads();
    int c = tid >> 2, j0 = (tid & 3) * 16;
    unsigned short* dst = (unsigned short*)(ws + WS_WUPT) +
                          (size_t)e * 65536 + (size_t)(ct * 64 + c) * 64 + j0;
    ushort4 o0, o1, o2, o3;
    o0.x = f2bf(tile[j0 + 0][c]);  o0.y = f2bf(tile[j0 + 1][c]);
    o0.z = f2bf(tile[j0 + 2][c]);  o0.w = f2bf(tile[j0 + 3][c]);
    o1.x = f2bf(tile[j0 + 4][c]);  o1.y = f2bf(tile[j0 + 5][c]);
    o1.z = f2bf(tile[j0 + 6][c]);  o1.w = f2bf(tile[j0 + 7][c]);
    o2.x = f2bf(tile[j0 + 8][c]);  o2.y = f2bf(tile[j0 + 9][c]);
    o2.z = f2bf(tile[j0 + 10][c]); o2.w = f2bf(tile[j0 + 11][c]);
    o3.x = f2bf(tile[j0 + 12][c]); o3.y = f2bf(tile[j0 + 13][c]);
    o3.z = f2bf(tile[j0 + 14][c]); o3.w = f2bf(tile[j0 + 15][c]);
    *(ushort4*)(dst + 0)  = o0;
    *(ushort4*)(dst + 4)  = o1;
    *(ushort4*)(dst + 8)  = o2;
    *(ushort4*)(dst + 12) = o3;
}

// K3: wave-per-token attention + routing. Registers + shuffles, minimal LDS.
__global__ __launch_bounds__(128) void k_attn(const float* __restrict__ pos_embed,
                                              const float* __restrict__ attn_in_w,
                                              const float* __restrict__ attn_in_b,
                                              const float* __restrict__ attn_out_w,
                                              const float* __restrict__ attn_out_b,
                                              const float* __restrict__ ln_w,
                                              const float* __restrict__ ln_b,
                                              const float* __restrict__ ls_w,
                                              const float* __restrict__ ls_b,
                                              float* __restrict__ ws) {
    int w = threadIdx.x >> 6;
    int l = threadIdx.x & 63;
    int n = blockIdx.x * 2 + w;
    int b = n >> 8;

    __shared__ float sq[2][SEQL][DLQ];   // seq broadcast buffer, reused for ctx

    // seq column l in registers + LDS broadcast copy
    float seqc[SEQL];
    const float* efp = ws + WS_EF + (size_t)n * DMODEL;
    seqc[0] = ws[WS_GCTX + b * DLQ + l];
#pragma unroll
    for (int i = 1; i <= NE; ++i)
        seqc[i] = efp[(i - 1) * DLQ + l] + pos_embed[(i - 1) * DLQ + l];
#pragma unroll
    for (int i = 0; i < SEQL; ++i) sq[w][i][l] = seqc[i];
    __syncthreads();

    // qkv: lane l computes q/k/v column l for all rows (broadcast LDS reads)
    float qc[SEQL], kc[SEQL], vc[SEQL];
#pragma unroll
    for (int i = 0; i < SEQL; ++i) { qc[i] = 0.f; kc[i] = 0.f; vc[i] = 0.f; }
    {
        const float* wq = attn_in_w + (size_t)l * DLQ;
        const float* wk = attn_in_w + (size_t)(64 + l) * DLQ;
        const float* wv = attn_in_w + (size_t)(128 + l) * DLQ;
        for (int j0 = 0; j0 < DLQ; j0 += 4) {
            float4 q4 = *(const float4*)(wq + j0);
            float4 k4 = *(const float4*)(wk + j0);
            float4 v4 = *(const float4*)(wv + j0);
#pragma unroll
            for (int i = 0; i < SEQL; ++i) {
                float4 s4 = *(const float4*)&sq[w][i][j0];
                qc[i] += s4.x * q4.x + s4.y * q4.y + s4.z * q4.z + s4.w * q4.w;
                kc[i] += s4.x * k4.x + s4.y * k4.y + s4.z * k4.z + s4.w * k4.w;
                vc[i] += s4.x * v4.x + s4.y * v4.y + s4.z * v4.z + s4.w * v4.w;
            }
        }
        float bq = attn_in_b[l], bk = attn_in_b[64 + l], bv = attn_in_b[128 + l];
#pragma unroll
        for (int i = 0; i < SEQL; ++i) { qc[i] += bq; kc[i] += bk; vc[i] += bv; }
    }
    __syncthreads();   // everyone done reading sq (it gets overwritten with ctx)

    // scores + softmax + ctx, per query row i. Group g=l>>4 computes head g
    // via 16-lane butterfly dot-products; softmax is lane-local over j-regs.
    for (int i = 0; i < SEQL; ++i) {
        float sj[SEQL];
#pragma unroll
        for (int j = 0; j < SEQL; ++j) {
            float p = qc[i] * kc[j];
            GSUM16(p);
            sj[j] = p * 0.25f;   // 1/sqrt(16)
        }
        float m = sj[0];
#pragma unroll
        for (int j = 1; j < SEQL; ++j) m = fmaxf(m, sj[j]);
        float ssum = 0.f;
#pragma unroll
        for (int j = 0; j < SEQL; ++j) { sj[j] = expf(sj[j] - m); ssum += sj[j]; }
        float inv = 1.f / ssum;
        float c = 0.f;
#pragma unroll
        for (int j = 0; j < SEQL; ++j) c += sj[j] * vc[j];
        sq[w][i][l] = c * inv;   // ctx column l
    }
    __syncthreads();

    // attn_out + residual -> rs[i] (column l)
    float rs[SEQL];
    {
        const float* wo = attn_out_w + (size_t)l * DLQ;
        float a[SEQL];
#pragma unroll
        for (int i = 0; i < SEQL; ++i) a[i] = 0.f;
        for (int j0 = 0; j0 < DLQ; j0 += 4) {
            float4 w4 = *(const float4*)(wo + j0);
#pragma unroll
            for (int i = 0; i < SEQL; ++i) {
                float4 c4 = *(const float4*)&sq[w][i][j0];
                a[i] += c4.x * w4.x + c4.y * w4.y + c4.z * w4.z + c4.w * w4.w;
            }
        }
        float bo = attn_out_b[l];
#pragma unroll
        for (int i = 0; i < SEQL; ++i) rs[i] = seqc[i] + a[i] + bo;
    }

    // LN + logits via 64-lane butterflies
    float c1 = ln_w[l] * ls_w[l];
    float c1sum = c1;        WSUM(c1sum);
    float c0 = ln_b[l] * ls_w[l];
    float c0sum = c0;        WSUM(c0sum);
    float lsb0 = ls_b[0];
    float p[NE];
    {
        float lgv[NE];
#pragma unroll
        for (int e = 0; e < NE; ++e) {
            float x = rs[e + 1];
            float s1 = x, s2 = x * x, s3 = x * c1;
            WSUM(s1); WSUM(s2); WSUM(s3);
            float mu = s1 * (1.0f / DLQ);
            float var = s2 * (1.0f / DLQ) - mu * mu;
            float rstd = rsqrtf(var + 1e-5f);
            lgv[e] = rstd * (s3 - mu * c1sum) + c0sum + lsb0 + ws[WS_GB + b * NE + e];
        }
        float m = lgv[0];
#pragma unroll
        for (int e = 1; e < NE; ++e) m = fmaxf(m, lgv[e]);
        float ssum = 0.f;
#pragma unroll
        for (int e = 0; e < NE; ++e) { p[e] = expf(lgv[e] - m); ssum += p[e]; }
        float inv = 1.f / ssum;
#pragma unroll
        for (int e = 0; e < NE; ++e) p[e] *= inv;
    }
    int t0 = 0; float b0 = p[0];
#pragma unroll
    for (int e = 1; e < NE; ++e) if (p[e] > b0) { b0 = p[e]; t0 = e; }
    int t1 = -1; float b1 = -1.f;
#pragma unroll
    for (int e = 0; e < NE; ++e) if (e != t0 && p[e] > b1) { b1 = p[e]; t1 = e; }

    if (l == 0) {
        float sw = b0 + b1;
        float tw0 = b0 / sw, tw1 = b1 / sw;
        ws[WS_TW + n * 2 + 0] = tw0;
        ws[WS_TW + n * 2 + 1] = tw1;
        int* ti = (int*)(ws + WS_TI);
        ti[n * 2 + 0] = t0;
        ti[n * 2 + 1] = t1;
#pragma unroll
        for (int e = 0; e < NE; ++e) ws[WS_PR + (size_t)n * NE + e] = p[e];
        // append to expert lists
        int* cnt  = (int*)(ws + WS_CNT);
        int* list = (int*)(ws + WS_LIST);
        float* lwp = ws + WS_LW;
        int i0 = atomicAdd(&cnt[t0], 1);
        list[t0 * 1024 + i0] = n * 2;
        lwp[t0 * 1024 + i0]  = tw0;
        int i1 = atomicAdd(&cnt[t1], 1);
        list[t1 * 1024 + i1] = n * 2 + 1;
        lwp[t1 * 1024 + i1]  = tw1;
    }
}

// K4: expert-major MoE GEMM. Block = (expert e, 64-col tile). 4 waves x 16 cols.
__global__ __launch_bounds__(256) void k_moe_gemm(float* __restrict__ ws) {
    int e = blockIdx.x, ct = blockIdx.y, tid = threadIdx.x;
    int cnt = ((const int*)(ws + WS_CNT))[e];
    if (cnt == 0) return;
    __shared__ __attribute__((aligned(16))) unsigned short act[16][72];  // padded rows
    __shared__ int toks[16];
    const int* list  = (const int*)(ws + WS_LIST) + e * 1024;
    const float* lwp = ws + WS_LW + e * 1024;
    const unsigned short* wupt = (const unsigned short*)(ws + WS_WUPT) + (size_t)e * 65536;
    int wv = tid >> 6, l = tid & 63;
    int col = ct * 64 + wv * 16 + (l & 15);
    int kb = (l >> 4) * 8;
    short8 bf0 = *(const short8*)(wupt + (size_t)col * 64 + kb);
    short8 bf1 = *(const short8*)(wupt + (size_t)col * 64 + 32 + kb);
    float* eo = ws + WS_EO;
    int gr = tid >> 4, gj = (tid & 15) * 4;

    for (int mt = 0; mt < cnt; mt += 16) {
        float a0 = 0.f, a1 = 0.f, a2 = 0.f, a3 = 0.f;
        int row = mt + gr;
        if (row < cnt) {
            int packed = list[row];
            float twv = lwp[row];
            const float* efr = ws + WS_EF + (size_t)(packed >> 1) * DMODEL + e * DLQ + gj;
            a0 = gelu_exact(efr[0]) * twv;
            a1 = gelu_exact(efr[1]) * twv;
            a2 = gelu_exact(efr[2]) * twv;
            a3 = gelu_exact(efr[3]) * twv;
        }
        __syncthreads();   // prior iteration's act reads complete
        act[gr][gj + 0] = f2bf(a0);
        act[gr][gj + 1] = f2bf(a1);
        act[gr][gj + 2] = f2bf(a2);
        act[gr][gj + 3] = f2bf(a3);
        if (tid < 16) toks[tid] = (mt + tid < cnt) ? list[mt + tid] : -1;
        __syncthreads();
        short8 af0 = *(const short8*)&act[l & 15][kb];
        short8 af1 = *(const short8*)&act[l & 15][32 + kb];
        f32x4 acc = {0.f, 0.f, 0.f, 0.f};
        acc = __builtin_amdgcn_mfma_f32_16x16x32_bf16(af0, bf0, acc, 0, 0, 0);
        acc = __builtin_amdgcn_mfma_f32_16x16x32_bf16(af1, bf1, acc, 0, 0, 0);
        int cr = (l >> 4) * 4;
#pragma unroll
        for (int r = 0; r < 4; ++r) {
            int pk = toks[cr + r];
            if (pk >= 0) eo[(size_t)pk * DMODEL + col] = acc[r];
        }
    }
}

// K5: combine the two expert slots per token
__global__ __launch_bounds__(256) void k_combine(const float* __restrict__ ws,
                                                 float* __restrict__ out) {
    int n = blockIdx.x, tid = threadIdx.x;
    const float* eo = ws + WS_EO;
    float4 a = *(const float4*)(eo + (size_t)(2 * n) * DMODEL + tid * 4);
    float4 b = *(const float4*)(eo + (size_t)(2 * n + 1) * DMODEL + tid * 4);
    float4 o = {a.x + b.x, a.y + b.y, a.z + b.z, a.w + b.w};
    *(float4*)(out + (size_t)n * DMODEL + tid * 4) = o;
}

// K6: aux loss from probs + top-k indices
__global__ __launch_bounds__(256) void k_aux(const float* __restrict__ ws, float* __restrict__ out) {
    int tid = threadIdx.x;
    __shared__ float sp[NE];
    __shared__ float scf[NE];
    if (tid < NE) { sp[tid] = 0.f; scf[tid] = 0.f; }
    __syncthreads();
    {
        int e = tid & 15, c = tid >> 4;
        float s = 0.f;
        for (int r = c * 64; r < c * 64 + 64; ++r) s += ws[WS_PR + (size_t)r * NE + e];
        atomicAdd(&sp[e], s);
    }
    {
        const int* ti = (const int*)(ws + WS_TI);
        for (int k = 0; k < 8; ++k) atomicAdd(&scf[ti[tid * 8 + k]], 1.0f);
    }
    __syncthreads();
    if (tid == 0) {
        float s = 0.f;
#pragma unroll
        for (int e = 0; e < NE; ++e) s += sp[e] * scf[e];
        out[(size_t)NTOK * DMODEL] = (float)NE * s / ((float)NTOK * (float)NTOK);
    }
}

extern "C" void kernel_launch(void* const* d_in, const int* in_sizes, int n_in,
                              void* d_out, int out_size, void* d_ws, size_t ws_size,
                              hipStream_t stream) {
    const float* x          = (const float*)d_in[0];
    const float* w_down     = (const float*)d_in[1];
    const float* pos_embed  = (const float*)d_in[2];
    const float* gp_w       = (const float*)d_in[3];
    const float* gp_b       = (const float*)d_in[4];
    const float* attn_in_w  = (const float*)d_in[5];
    const float* attn_in_b  = (const float*)d_in[6];
    const float* attn_out_w = (const float*)d_in[7];
    const float* attn_out_b = (const float*)d_in[8];
    const float* ln_w       = (const float*)d_in[9];
    const float* ln_b       = (const float*)d_in[10];
    const float* ls_w       = (const float*)d_in[11];
    const float* ls_b       = (const float*)d_in[12];
    const float* g1_w       = (const float*)d_in[13];
    const float* g1_b       = (const float*)d_in[14];
    const float* g2_w       = (const float*)d_in[15];
    const float* g2_b       = (const float*)d_in[16];
    const float* w_up       = (const float*)d_in[17];
    float* ws  = (float*)d_ws;
    float* out = (float*)d_out;

    k_prep<<<dim3(1024, 2), 256, 0, stream>>>(x, w_down, ws);
    k_batch_partial<<<32, 256, 0, stream>>>(x, ws);
    k_global_ctx<<<NB, 256, 0, stream>>>(gp_w, gp_b, g1_w, g1_b, g2_w, g2_b, ws);
    k_ef_mfma<<<dim3(16, 16), 256, 0, stream>>>(ws);
    k_prep_wup<<<dim3(16, 16), 256, 0, stream>>>(w_up, ws);
    k_attn<<<512, 128, 0, stream>>>(pos_embed, attn_in_w, attn_in_b, attn_out_w, attn_out_b,
                                    ln_w, ln_b, ls_w, ls_b, ws);
    k_moe_gemm<<<dim3(NE, 16), 256, 0, stream>>>(ws);
    k_combine<<<NTOK, 256, 0, stream>>>(ws, out);
    k_aux<<<1, 256, 0, stream>>>(ws, out);
}

// Round 4
// 223.506 us; speedup vs baseline: 1.1986x; 1.1986x over previous
//
#include <hip/hip_runtime.h>
#include <math.h>

// Problem constants
#define NB 4
#define TT 256
#define DMODEL 1024
#define NE 16
#define DLQ 64
#define NH 4
#define HD 16
#define SEQL 17
#define NTOK 1024   // NB*TT

// Workspace layout (float offsets). Proven budget: round-3 passed with end
// 4,227,392 floats. Overlays by phase:
//   Ah/Al/Bh/Bl + P1 die after ef_combine; WUPT/CNT/LIST/LW/aiwF/aowF overlay
//   P1; EO overlays Ah/Al/Bh (written by k_moe_gemm at the end).
static constexpr size_t WS_EF    = 0;          // 1024x1024 fp32 ef (= P0 during GEMM)
static constexpr size_t WS_AH    = 1048576;    // x hi bf16 plane, frag-swizzled
static constexpr size_t WS_AL    = 1572864;    // x lo
static constexpr size_t WS_BH    = 2097152;    // w_down hi
static constexpr size_t WS_BL    = 2621440;    // w_down lo
static constexpr size_t WS_P1    = 3145728;    // K-split partial (1M floats)
static constexpr size_t WS_EO    = 1048576;    // 2048x1024 fp32 eo (late)
static constexpr size_t WS_WUPT  = 3145728;    // w_up^T bf16 [16][1024][64] (late)
static constexpr size_t WS_CNT   = 3670016;    // 16 int expert counters
static constexpr size_t WS_LIST  = 3670032;    // 16x1024 int packed (tok*2+slot)
static constexpr size_t WS_LW    = 3686416;    // 16x1024 float weights
static constexpr size_t WS_AIWFH = 3702800;    // attn_in_w hi frags  (12288 sh)
static constexpr size_t WS_AIWFL = 3708944;    // attn_in_w lo frags
static constexpr size_t WS_AOWFH = 3715088;    // attn_out_w hi frags (4096 sh)
static constexpr size_t WS_AOWFL = 3717136;    // attn_out_w lo frags
static constexpr size_t WS_XPART = 4194304;    // 32x1024 batch partials (early)
static constexpr size_t WS_PR    = 4194304;    // 1024x16 probs (late, overlays XPART)
static constexpr size_t WS_TW    = 4210688;    // 1024x2 top-k weights
static constexpr size_t WS_TI    = 4212736;    // 1024x2 top-k indices (int)
static constexpr size_t WS_GCTX  = 4227072;    // 4x64
static constexpr size_t WS_GB    = 4227328;    // 4x16

typedef __attribute__((ext_vector_type(8))) short short8;
typedef __attribute__((ext_vector_type(4))) float f32x4;

__device__ __forceinline__ float gelu_exact(float x) {
    return 0.5f * x * (1.0f + erff(x * 0.70710678118654752f));
}

__device__ __forceinline__ unsigned short f2bf(float f) {
    unsigned int u = __float_as_uint(f);
    unsigned int r = (u + 0x7fffu + ((u >> 16) & 1u)) >> 16;
    return (unsigned short)r;
}
__device__ __forceinline__ float bf2f(unsigned short h) {
    return __uint_as_float(((unsigned int)h) << 16);
}

#define WSUM(v) { v += __shfl_xor(v,1); v += __shfl_xor(v,2); v += __shfl_xor(v,4); \
                  v += __shfl_xor(v,8); v += __shfl_xor(v,16); v += __shfl_xor(v,32); }
#define GSUM16(v) { v += __shfl_xor(v,1); v += __shfl_xor(v,2); v += __shfl_xor(v,4); \
                    v += __shfl_xor(v,8); }

// K0: split x / w_down into hi/lo bf16 planes, stored FRAG-SWIZZLED:
// plane[(nb*16+kb)*4096 + st*1024 + ks*512 + lane*8 + j] where
// nb=row/64, kb=col/64, st=(row%64)/16, ks=(col%64)/32,
// lane=(row%16)+((col%32)/8)*16, j=col%8. This makes global_load_lds a
// contiguous copy and ds_read_b128 frag reads conflict-free.
__global__ __launch_bounds__(256) void k_prep(const float* __restrict__ x,
                                              const float* __restrict__ wdn,
                                              float* __restrict__ ws) {
    int t = blockIdx.x * 256 + threadIdx.x;   // 0..131071
    int row = t >> 7;
    int col0 = (t & 127) * 8;
    const float* src = blockIdx.y ? wdn : x;
    unsigned short* hp = (unsigned short*)(ws + (blockIdx.y ? WS_BH : WS_AH));
    unsigned short* lp = (unsigned short*)(ws + (blockIdx.y ? WS_BL : WS_AL));
    float4 v0 = *(const float4*)(src + (size_t)row * DMODEL + col0);
    float4 v1 = *(const float4*)(src + (size_t)row * DMODEL + col0 + 4);
    float vv[8] = {v0.x, v0.y, v0.z, v0.w, v1.x, v1.y, v1.z, v1.w};
    unsigned short h8[8], l8[8];
#pragma unroll
    for (int j = 0; j < 8; ++j) {
        h8[j] = f2bf(vv[j]);
        l8[j] = f2bf(vv[j] - bf2f(h8[j]));
    }
    int nb = row >> 6, kb = col0 >> 6;
    int st = (row & 63) >> 4;
    int ks = (col0 & 63) >> 5;
    int ln = (row & 15) + (((col0 >> 3) & 3) << 4);
    size_t off = (size_t)(nb * 16 + kb) * 4096 + st * 1024 + ks * 512 + ln * 8;
    *(short8*)(hp + off) = *(short8*)h8;
    *(short8*)(lp + off) = *(short8*)l8;
}

// K1a: per-(batch, slice) column sums of x
__global__ __launch_bounds__(256) void k_batch_partial(const float* __restrict__ x,
                                                       float* __restrict__ ws) {
    int b = blockIdx.x >> 3;
    int g = blockIdx.x & 7;
    int tid = threadIdx.x;
    const float* xp = x + (size_t)b * TT * DMODEL + (size_t)g * 32 * DMODEL + tid * 4;
    float4 acc = {0.f, 0.f, 0.f, 0.f};
#pragma unroll 4
    for (int t = 0; t < 32; ++t) {
        float4 v = *(const float4*)(xp + (size_t)t * DMODEL);
        acc.x += v.x; acc.y += v.y; acc.z += v.z; acc.w += v.w;
    }
    *(float4*)(ws + WS_XPART + (size_t)blockIdx.x * DMODEL + tid * 4) = acc;
}

// K1b: per batch: xmean -> gctx -> gelu MLP -> gb
__global__ __launch_bounds__(256) void k_global_ctx(const float* __restrict__ gp_w,
                                                    const float* __restrict__ gp_b,
                                                    const float* __restrict__ g1_w,
                                                    const float* __restrict__ g1_b,
                                                    const float* __restrict__ g2_w,
                                                    const float* __restrict__ g2_b,
                                                    float* __restrict__ ws) {
    int b = blockIdx.x, tid = threadIdx.x;
    __shared__ float xm[DMODEL];
    __shared__ float gc[DLQ];
    __shared__ float gb1[128];
    float4 a = {0.f, 0.f, 0.f, 0.f};
#pragma unroll
    for (int g = 0; g < 8; ++g) {
        float4 v = *(const float4*)(ws + WS_XPART + (size_t)(b * 8 + g) * DMODEL + tid * 4);
        a.x += v.x; a.y += v.y; a.z += v.z; a.w += v.w;
    }
    const float inv_t = 1.0f / (float)TT;
    xm[tid * 4 + 0] = a.x * inv_t;
    xm[tid * 4 + 1] = a.y * inv_t;
    xm[tid * 4 + 2] = a.z * inv_t;
    xm[tid * 4 + 3] = a.w * inv_t;
    __syncthreads();
    if (tid < DLQ) {
        const float* wr = gp_w + (size_t)tid * DMODEL;
        float s = 0.f;
        for (int j = 0; j < DMODEL; j += 4) {
            float4 w4 = *(const float4*)(wr + j);
            float4 x4 = *(const float4*)&xm[j];
            s += w4.x * x4.x + w4.y * x4.y + w4.z * x4.z + w4.w * x4.w;
        }
        float v = s + gp_b[tid];
        gc[tid] = v;
        ws[WS_GCTX + b * DLQ + tid] = v;
    }
    __syncthreads();
    if (tid < 128) {
        const float* wr = g1_w + (size_t)tid * DLQ;
        float s = 0.f;
        for (int j = 0; j < DLQ; j += 4) {
            float4 w4 = *(const float4*)(wr + j);
            float4 x4 = *(const float4*)&gc[j];
            s += w4.x * x4.x + w4.y * x4.y + w4.z * x4.z + w4.w * x4.w;
        }
        gb1[tid] = gelu_exact(s + g1_b[tid]);
    }
    __syncthreads();
    if (tid < NE) {
        const float* wr = g2_w + (size_t)tid * 128;
        float s = 0.f;
        for (int j = 0; j < 128; ++j) s += wr[j] * gb1[j];
        ws[WS_GB + b * NE + tid] = s + g2_b[tid];
    }
}

// K2: ef GEMM. 64x64 tile, K=1024 split over 2 blocks (z), BK=64.
// 3-term hi/lo: x.w = xh.wh + xl.wh + xh.wl. Frag-swizzled operands:
// staging is contiguous DMA; all ds_read_b128 conflict-free.
__global__ __launch_bounds__(256) void k_ef_mfma(float* __restrict__ ws) {
    __shared__ __attribute__((aligned(16))) unsigned short smem[16384];  // 4 x 8KB
    const unsigned short* AhP = (const unsigned short*)(ws + WS_AH);
    const unsigned short* AlP = (const unsigned short*)(ws + WS_AL);
    const unsigned short* BhP = (const unsigned short*)(ws + WS_BH);
    const unsigned short* BlP = (const unsigned short*)(ws + WS_BL);
    int tid = threadIdx.x;
    int mb = blockIdx.x;       // w_down tile (C cols)
    int nb = blockIdx.y;       // x tile (C rows)
    int kz = blockIdx.z;
    int w = tid >> 6, l = tid & 63;
    int wn = (w >> 1) * 32, wm = (w & 1) * 32;
    int stA = wn >> 4, stB = wm >> 4;
    f32x4 acc00 = {0.f, 0.f, 0.f, 0.f}, acc01 = acc00, acc10 = acc00, acc11 = acc00;

    for (int it = 0; it < 8; ++it) {
        int kb = kz * 8 + it;
        const char* srcA_h = (const char*)(AhP + (size_t)(nb * 16 + kb) * 4096);
        const char* srcA_l = (const char*)(AlP + (size_t)(nb * 16 + kb) * 4096);
        const char* srcB_h = (const char*)(BhP + (size_t)(mb * 16 + kb) * 4096);
        const char* srcB_l = (const char*)(BlP + (size_t)(mb * 16 + kb) * 4096);
        const char* srcs[4] = {srcA_h, srcA_l, srcB_h, srcB_l};
#pragma unroll
        for (int p = 0; p < 4; ++p) {
#pragma unroll
            for (int h = 0; h < 2; ++h) {
                __builtin_amdgcn_global_load_lds(
                    (const __attribute__((address_space(1))) void*)(srcs[p] + h * 4096 + tid * 16),
                    (__attribute__((address_space(3))) void*)((char*)smem + p * 8192 + h * 4096 + tid * 16),
                    16, 0, 0);
            }
        }
        __syncthreads();
        const unsigned short* Ah = smem;
        const unsigned short* Al = smem + 4096;
        const unsigned short* Bh = smem + 8192;
        const unsigned short* Bl = smem + 12288;
#pragma unroll
        for (int ks = 0; ks < 2; ++ks) {
            short8 ah0 = *(const short8*)(Ah + (stA + 0) * 1024 + ks * 512 + l * 8);
            short8 ah1 = *(const short8*)(Ah + (stA + 1) * 1024 + ks * 512 + l * 8);
            short8 al0 = *(const short8*)(Al + (stA + 0) * 1024 + ks * 512 + l * 8);
            short8 al1 = *(const short8*)(Al + (stA + 1) * 1024 + ks * 512 + l * 8);
            short8 bh0 = *(const short8*)(Bh + (stB + 0) * 1024 + ks * 512 + l * 8);
            short8 bh1 = *(const short8*)(Bh + (stB + 1) * 1024 + ks * 512 + l * 8);
            short8 bl0 = *(const short8*)(Bl + (stB + 0) * 1024 + ks * 512 + l * 8);
            short8 bl1 = *(const short8*)(Bl + (stB + 1) * 1024 + ks * 512 + l * 8);
            acc00 = __builtin_amdgcn_mfma_f32_16x16x32_bf16(ah0, bh0, acc00, 0, 0, 0);
            acc00 = __builtin_amdgcn_mfma_f32_16x16x32_bf16(al0, bh0, acc00, 0, 0, 0);
            acc00 = __builtin_amdgcn_mfma_f32_16x16x32_bf16(ah0, bl0, acc00, 0, 0, 0);
            acc01 = __builtin_amdgcn_mfma_f32_16x16x32_bf16(ah0, bh1, acc01, 0, 0, 0);
            acc01 = __builtin_amdgcn_mfma_f32_16x16x32_bf16(al0, bh1, acc01, 0, 0, 0);
            acc01 = __builtin_amdgcn_mfma_f32_16x16x32_bf16(ah0, bl1, acc01, 0, 0, 0);
            acc10 = __builtin_amdgcn_mfma_f32_16x16x32_bf16(ah1, bh0, acc10, 0, 0, 0);
            acc10 = __builtin_amdgcn_mfma_f32_16x16x32_bf16(al1, bh0, acc10, 0, 0, 0);
            acc10 = __builtin_amdgcn_mfma_f32_16x16x32_bf16(ah1, bl0, acc10, 0, 0, 0);
            acc11 = __builtin_amdgcn_mfma_f32_16x16x32_bf16(ah1, bh1, acc11, 0, 0, 0);
            acc11 = __builtin_amdgcn_mfma_f32_16x16x32_bf16(al1, bh1, acc11, 0, 0, 0);
            acc11 = __builtin_amdgcn_mfma_f32_16x16x32_bf16(ah1, bl1, acc11, 0, 0, 0);
        }
        __syncthreads();
    }
    // C layout: col = lane&15, row = (lane>>4)*4 + reg
    int cr = (l >> 4) * 4, cc = l & 15;
    int n0 = nb * 64, m0 = mb * 64;
    float* P = ws + (kz == 0 ? WS_EF : WS_P1);
#pragma unroll
    for (int r = 0; r < 4; ++r) {
        P[(size_t)(n0 + wn + cr + r) * DMODEL + (m0 + wm + cc)]           = acc00[r];
        P[(size_t)(n0 + wn + cr + r) * DMODEL + (m0 + wm + 16 + cc)]      = acc01[r];
        P[(size_t)(n0 + wn + 16 + cr + r) * DMODEL + (m0 + wm + cc)]      = acc10[r];
        P[(size_t)(n0 + wn + 16 + cr + r) * DMODEL + (m0 + wm + 16 + cc)] = acc11[r];
    }
}

// K2c: EF += P1 (K-split combine, in place)
__global__ __launch_bounds__(256) void k_ef_combine(float* __restrict__ ws) {
    size_t i = ((size_t)blockIdx.x * 256 + threadIdx.x) * 4;
    float4 a = *(const float4*)(ws + WS_EF + i);
    float4 b = *(const float4*)(ws + WS_P1 + i);
    float4 o = {a.x + b.x, a.y + b.y, a.z + b.z, a.w + b.w};
    *(float4*)(ws + WS_EF + i) = o;
}

// K2b: transpose w_up -> bf16 w_up^T [e][col][j]; also zero expert counters.
__global__ __launch_bounds__(256) void k_prep_wup(const float* __restrict__ w_up,
                                                  float* __restrict__ ws) {
    int e = blockIdx.x, ct = blockIdx.y, tid = threadIdx.x;
    __shared__ float tile[64][65];
#pragma unroll
    for (int jj = 0; jj < 16; ++jj) {
        int j = jj * 4 + (tid >> 6);
        tile[j][tid & 63] = w_up[((size_t)e * DLQ + j) * DMODEL + ct * 64 + (tid & 63)];
    }
    if (e == 0 && ct == 0 && tid < 16) ((int*)(ws + WS_CNT))[tid] = 0;
    __syncthreads();
    int c = tid >> 2, j0 = (tid & 3) * 16;
    unsigned short* dst = (unsigned short*)(ws + WS_WUPT) +
                          (size_t)e * 65536 + (size_t)(ct * 64 + c) * 64 + j0;
#pragma unroll
    for (int q = 0; q < 4; ++q) {
        ushort4 o;
        o.x = f2bf(tile[j0 + q * 4 + 0][c]);
        o.y = f2bf(tile[j0 + q * 4 + 1][c]);
        o.z = f2bf(tile[j0 + q * 4 + 2][c]);
        o.w = f2bf(tile[j0 + q * 4 + 3][c]);
        *(ushort4*)(dst + q * 4) = o;
    }
}

// K2d: attn weights -> hi/lo B-frag planes.
// aiwF: [nt(12)][kf(2)][lane(64)][8]; aowF: [nt(4)][kf(2)][lane(64)][8]
__global__ __launch_bounds__(256) void k_prep_attnw(const float* __restrict__ aiw,
                                                    const float* __restrict__ aow,
                                                    float* __restrict__ ws) {
    int tid = threadIdx.x;
    unsigned short* fh = (unsigned short*)(ws + WS_AIWFH);
    unsigned short* fl = (unsigned short*)(ws + WS_AIWFL);
    for (int idx = tid; idx < 12 * 2 * 64; idx += 256) {
        int nt = idx >> 7, kf = (idx >> 6) & 1, l = idx & 63;
        int row = nt * 16 + (l & 15);
        int k = kf * 32 + ((l >> 4) << 3);
        const float* src = aiw + (size_t)row * DLQ + k;
        unsigned short h8[8], l8[8];
#pragma unroll
        for (int j = 0; j < 8; ++j) {
            h8[j] = f2bf(src[j]);
            l8[j] = f2bf(src[j] - bf2f(h8[j]));
        }
        size_t off = (size_t)(nt * 2 + kf) * 512 + l * 8;
        *(short8*)(fh + off) = *(short8*)h8;
        *(short8*)(fl + off) = *(short8*)l8;
    }
    unsigned short* gh = (unsigned short*)(ws + WS_AOWFH);
    unsigned short* gl = (unsigned short*)(ws + WS_AOWFL);
    for (int idx = tid; idx < 4 * 2 * 64; idx += 256) {
        int nt = idx >> 7, kf = (idx >> 6) & 1, l = idx & 63;
        int row = nt * 16 + (l & 15);
        int k = kf * 32 + ((l >> 4) << 3);
        const float* src = aow + (size_t)row * DLQ + k;
        unsigned short h8[8], l8[8];
#pragma unroll
        for (int j = 0; j < 8; ++j) {
            h8[j] = f2bf(src[j]);
            l8[j] = f2bf(src[j] - bf2f(h8[j]));
        }
        size_t off = (size_t)(nt * 2 + kf) * 512 + l * 8;
        *(short8*)(gh + off) = *(short8*)h8;
        *(short8*)(gl + off) = *(short8*)l8;
    }
}

// K3: one token per block (128 thr = 2 waves). MFMA qkv + attn_out,
// shuffle scores/softmax/ctx, butterfly LN/logits, routing.
__global__ __launch_bounds__(128) void k_attn2(const float* __restrict__ pos_embed,
                                               const float* __restrict__ attn_in_b,
                                               const float* __restrict__ attn_out_b,
                                               const float* __restrict__ ln_w,
                                               const float* __restrict__ ln_b,
                                               const float* __restrict__ ls_w,
                                               const float* __restrict__ ls_b,
                                               float* __restrict__ ws) {
    int n = blockIdx.x;
    int w = threadIdx.x >> 6;
    int l = threadIdx.x & 63;
    int b = n >> 8;

    __shared__ unsigned short sH[2048], sL[2048];        // seq frags [mt2][kf2][64][8]
    __shared__ unsigned short ctxH[1024], ctxL[1024];    // ctx frags [kf2][64][8]
    __shared__ float qkv[SEQL * 200];
    __shared__ float ao[16 * 72];

    // Phase 1: build seq column l in regs; write hi/lo frag-linear LDS (split rows by wave)
    float seqc[SEQL];
    {
        const float* efp = ws + WS_EF + (size_t)n * DMODEL;
        float gcv = ws[WS_GCTX + b * DLQ + l];
#pragma unroll
        for (int i = 0; i < SEQL; ++i) {
            float s = (i == 0) ? gcv : efp[(i - 1) * DLQ + l] + pos_embed[(i - 1) * DLQ + l];
            seqc[i] = s;
            int lo_r = w * 9, hi_r = w * 9 + 8;   // wave0: 0..8, wave1: 9..16
            if (i >= lo_r && i <= hi_r && i < SEQL) {
                unsigned short hs = f2bf(s);
                unsigned short lsv = f2bf(s - bf2f(hs));
                int mt = i >> 4;
                int ls = (i & 15) + (((l >> 3) & 3) << 4);
                int kf = l >> 5;
                int j = l & 7;
                size_t off = (size_t)(mt * 2 + kf) * 512 + ls * 8 + j;
                sH[off] = hs;
                sL[off] = lsv;
            }
        }
    }
    __syncthreads();

    // Phase 2: qkv = seq @ aiw^T via MFMA. Wave w handles N-tiles w*6..w*6+5.
    {
        const unsigned short* fh = (const unsigned short*)(ws + WS_AIWFH);
        const unsigned short* fl = (const unsigned short*)(ws + WS_AIWFL);
        f32x4 acc[6][2];
#pragma unroll
        for (int t = 0; t < 6; ++t)
#pragma unroll
            for (int m = 0; m < 2; ++m) acc[t][m] = (f32x4){0.f, 0.f, 0.f, 0.f};
#pragma unroll
        for (int kf = 0; kf < 2; ++kf) {
            short8 ah0 = *(const short8*)(sH + (0 * 2 + kf) * 512 + l * 8);
            short8 ah1 = *(const short8*)(sH + (1 * 2 + kf) * 512 + l * 8);
            short8 al0 = *(const short8*)(sL + (0 * 2 + kf) * 512 + l * 8);
            short8 al1 = *(const short8*)(sL + (1 * 2 + kf) * 512 + l * 8);
#pragma unroll
            for (int t = 0; t < 6; ++t) {
                int nt = w * 6 + t;
                short8 bh = *(const short8*)(fh + (size_t)(nt * 2 + kf) * 512 + l * 8);
                short8 bl = *(const short8*)(fl + (size_t)(nt * 2 + kf) * 512 + l * 8);
                acc[t][0] = __builtin_amdgcn_mfma_f32_16x16x32_bf16(ah0, bh, acc[t][0], 0, 0, 0);
                acc[t][0] = __builtin_amdgcn_mfma_f32_16x16x32_bf16(al0, bh, acc[t][0], 0, 0, 0);
                acc[t][0] = __builtin_amdgcn_mfma_f32_16x16x32_bf16(ah0, bl, acc[t][0], 0, 0, 0);
                acc[t][1] = __builtin_amdgcn_mfma_f32_16x16x32_bf16(ah1, bh, acc[t][1], 0, 0, 0);
                acc[t][1] = __builtin_amdgcn_mfma_f32_16x16x32_bf16(al1, bh, acc[t][1], 0, 0, 0);
                acc[t][1] = __builtin_amdgcn_mfma_f32_16x16x32_bf16(ah1, bl, acc[t][1], 0, 0, 0);
            }
        }
#pragma unroll
        for (int t = 0; t < 6; ++t) {
            int col = (w * 6 + t) * 16 + (l & 15);
            float bias = attn_in_b[col];
#pragma unroll
            for (int r = 0; r < 4; ++r) {
                int row = (l >> 4) * 4 + r;
                qkv[row * 200 + col] = acc[t][0][r] + bias;
            }
            if ((l >> 4) == 0) qkv[16 * 200 + col] = acc[t][1][0] + bias;
        }
    }
    __syncthreads();

    // Phase 3: scores (16-lane butterfly per head g=l>>4), softmax, ctx.
    // Wave w handles query rows i = w*8+1 .. w*8+8; ctx col l.
    {
        int g = l >> 4;
        float kc[SEQL], vc[SEQL];
#pragma unroll
        for (int j = 0; j < SEQL; ++j) {
            kc[j] = qkv[j * 200 + 64 + g * 16 + (l & 15)];
            vc[j] = qkv[j * 200 + 128 + l];
        }
        for (int i = w * 8 + 1; i <= w * 8 + 8; ++i) {
            float qi = qkv[i * 200 + g * 16 + (l & 15)];
            float sj[SEQL];
#pragma unroll
            for (int j = 0; j < SEQL; ++j) {
                float p = qi * kc[j];
                GSUM16(p);
                sj[j] = p * 0.25f;
            }
            float m = sj[0];
#pragma unroll
            for (int j = 1; j < SEQL; ++j) m = fmaxf(m, sj[j]);
            float ssum = 0.f;
#pragma unroll
            for (int j = 0; j < SEQL; ++j) { sj[j] = expf(sj[j] - m); ssum += sj[j]; }
            float inv = 1.f / ssum;
            float c = 0.f;
#pragma unroll
            for (int j = 0; j < SEQL; ++j) c += sj[j] * vc[j];
            c *= inv;
            // write ctx row i-1, col l in frag-linear hi/lo
            unsigned short ch = f2bf(c);
            unsigned short cl = f2bf(c - bf2f(ch));
            int ls = ((i - 1) & 15) + (((l >> 3) & 3) << 4);
            int kf = l >> 5;
            int j2 = l & 7;
            size_t off = (size_t)kf * 512 + ls * 8 + j2;
            ctxH[off] = ch;
            ctxL[off] = cl;
        }
    }
    __syncthreads();

    // Phase 4: attn_out = ctx @ aow^T via MFMA. Wave w: N-tiles {2w, 2w+1}.
    {
        const unsigned short* gh = (const unsigned short*)(ws + WS_AOWFH);
        const unsigned short* gl = (const unsigned short*)(ws + WS_AOWFL);
        f32x4 acc[2];
        acc[0] = (f32x4){0.f, 0.f, 0.f, 0.f};
        acc[1] = acc[0];
#pragma unroll
        for (int kf = 0; kf < 2; ++kf) {
            short8 ah = *(const short8*)(ctxH + kf * 512 + l * 8);
            short8 al = *(const short8*)(ctxL + kf * 512 + l * 8);
#pragma unroll
            for (int t = 0; t < 2; ++t) {
                int nt = w * 2 + t;
                short8 bh = *(const short8*)(gh + (size_t)(nt * 2 + kf) * 512 + l * 8);
                short8 bl = *(const short8*)(gl + (size_t)(nt * 2 + kf) * 512 + l * 8);
                acc[t] = __builtin_amdgcn_mfma_f32_16x16x32_bf16(ah, bh, acc[t], 0, 0, 0);
                acc[t] = __builtin_amdgcn_mfma_f32_16x16x32_bf16(al, bh, acc[t], 0, 0, 0);
                acc[t] = __builtin_amdgcn_mfma_f32_16x16x32_bf16(ah, bl, acc[t], 0, 0, 0);
            }
        }
#pragma unroll
        for (int t = 0; t < 2; ++t) {
            int col = (w * 2 + t) * 16 + (l & 15);
            float bias = attn_out_b[col];
#pragma unroll
            for (int r = 0; r < 4; ++r) {
                int row = (l >> 4) * 4 + r;   // ctx row = seq row-1
                ao[row * 72 + col] = acc[t][r] + bias;
            }
        }
    }
    __syncthreads();

    // Phase 5: residual + LN + logits + softmax + top2 (both waves duplicate)
    float rs[SEQL];
#pragma unroll
    for (int i = 1; i < SEQL; ++i) rs[i] = seqc[i] + ao[(i - 1) * 72 + l];

    float c1 = ln_w[l] * ls_w[l];
    float c1sum = c1;        WSUM(c1sum);
    float c0 = ln_b[l] * ls_w[l];
    float c0sum = c0;        WSUM(c0sum);
    float lsb0 = ls_b[0];
    float p[NE];
    {
        float lgv[NE];
#pragma unroll
        for (int e = 0; e < NE; ++e) {
            float x = rs[e + 1];
            float s1 = x, s2 = x * x, s3 = x * c1;
            WSUM(s1); WSUM(s2); WSUM(s3);
            float mu = s1 * (1.0f / DLQ);
            float var = s2 * (1.0f / DLQ) - mu * mu;
            float rstd = rsqrtf(var + 1e-5f);
            lgv[e] = rstd * (s3 - mu * c1sum) + c0sum + lsb0 + ws[WS_GB + b * NE + e];
        }
        float m = lgv[0];
#pragma unroll
        for (int e = 1; e < NE; ++e) m = fmaxf(m, lgv[e]);
        float ssum = 0.f;
#pragma unroll
        for (int e = 0; e < NE; ++e) { p[e] = expf(lgv[e] - m); ssum += p[e]; }
        float inv = 1.f / ssum;
#pragma unroll
        for (int e = 0; e < NE; ++e) p[e] *= inv;
    }
    int t0 = 0; float b0 = p[0];
#pragma unroll
    for (int e = 1; e < NE; ++e) if (p[e] > b0) { b0 = p[e]; t0 = e; }
    int t1 = -1; float b1 = -1.f;
#pragma unroll
    for (int e = 0; e < NE; ++e) if (e != t0 && p[e] > b1) { b1 = p[e]; t1 = e; }

    if (w == 0 && l == 0) {
        float sw = b0 + b1;
        float tw0 = b0 / sw, tw1 = b1 / sw;
        ws[WS_TW + n * 2 + 0] = tw0;
        ws[WS_TW + n * 2 + 1] = tw1;
        int* ti = (int*)(ws + WS_TI);
        ti[n * 2 + 0] = t0;
        ti[n * 2 + 1] = t1;
#pragma unroll
        for (int e = 0; e < NE; ++e) ws[WS_PR + (size_t)n * NE + e] = p[e];
        int* cnt  = (int*)(ws + WS_CNT);
        int* list = (int*)(ws + WS_LIST);
        float* lwp = ws + WS_LW;
        int i0 = atomicAdd(&cnt[t0], 1);
        list[t0 * 1024 + i0] = n * 2;
        lwp[t0 * 1024 + i0]  = tw0;
        int i1 = atomicAdd(&cnt[t1], 1);
        list[t1 * 1024 + i1] = n * 2 + 1;
        lwp[t1 * 1024 + i1]  = tw1;
    }
}

// K4: expert-major MoE GEMM. Block = (expert e, 64-col tile). 4 waves x 16 cols.
__global__ __launch_bounds__(256) void k_moe_gemm(float* __restrict__ ws) {
    int e = blockIdx.x, ct = blockIdx.y, tid = threadIdx.x;
    int cnt = ((const int*)(ws + WS_CNT))[e];
    if (cnt == 0) return;
    __shared__ __attribute__((aligned(16))) unsigned short act[16][72];
    __shared__ int toks[16];
    const int* list  = (const int*)(ws + WS_LIST) + e * 1024;
    const float* lwp = ws + WS_LW + e * 1024;
    const unsigned short* wupt = (const unsigned short*)(ws + WS_WUPT) + (size_t)e * 65536;
    int wv = tid >> 6, l = tid & 63;
    int col = ct * 64 + wv * 16 + (l & 15);
    int kb = (l >> 4) * 8;
    short8 bf0 = *(const short8*)(wupt + (size_t)col * 64 + kb);
    short8 bf1 = *(const short8*)(wupt + (size_t)col * 64 + 32 + kb);
    float* eo = ws + WS_EO;
    int gr = tid >> 4, gj = (tid & 15) * 4;

    for (int mt = 0; mt < cnt; mt += 16) {
        float a0 = 0.f, a1 = 0.f, a2 = 0.f, a3 = 0.f;
        int row = mt + gr;
        if (row < cnt) {
            int packed = list[row];
            float twv = lwp[row];
            const float* efr = ws + WS_EF + (size_t)(packed >> 1) * DMODEL + e * DLQ + gj;
            a0 = gelu_exact(efr[0]) * twv;
            a1 = gelu_exact(efr[1]) * twv;
            a2 = gelu_exact(efr[2]) * twv;
            a3 = gelu_exact(efr[3]) * twv;
        }
        __syncthreads();
        act[gr][gj + 0] = f2bf(a0);
        act[gr][gj + 1] = f2bf(a1);
        act[gr][gj + 2] = f2bf(a2);
        act[gr][gj + 3] = f2bf(a3);
        if (tid < 16) toks[tid] = (mt + tid < cnt) ? list[mt + tid] : -1;
        __syncthreads();
        short8 af0 = *(const short8*)&act[l & 15][kb];
        short8 af1 = *(const short8*)&act[l & 15][32 + kb];
        f32x4 acc = {0.f, 0.f, 0.f, 0.f};
        acc = __builtin_amdgcn_mfma_f32_16x16x32_bf16(af0, bf0, acc, 0, 0, 0);
        acc = __builtin_amdgcn_mfma_f32_16x16x32_bf16(af1, bf1, acc, 0, 0, 0);
        int cr = (l >> 4) * 4;
#pragma unroll
        for (int r = 0; r < 4; ++r) {
            int pk = toks[cr + r];
            if (pk >= 0) eo[(size_t)pk * DMODEL + col] = acc[r];
        }
    }
}

// K5: combine the two expert slots per token
__global__ __launch_bounds__(256) void k_combine(const float* __restrict__ ws,
                                                 float* __restrict__ out) {
    int n = blockIdx.x, tid = threadIdx.x;
    const float* eo = ws + WS_EO;
    float4 a = *(const float4*)(eo + (size_t)(2 * n) * DMODEL + tid * 4);
    float4 b = *(const float4*)(eo + (size_t)(2 * n + 1) * DMODEL + tid * 4);
    float4 o = {a.x + b.x, a.y + b.y, a.z + b.z, a.w + b.w};
    *(float4*)(out + (size_t)n * DMODEL + tid * 4) = o;
}

// K6: aux loss. Contiguous PR reads, counts from expert lists.
__global__ __launch_bounds__(256) void k_aux(const float* __restrict__ ws, float* __restrict__ out) {
    int tid = threadIdx.x;
    __shared__ float wsum[4][NE];
    float p[NE];
#pragma unroll
    for (int e = 0; e < NE; ++e) p[e] = 0.f;
    const float* pr = ws + WS_PR + (size_t)tid * 64;   // 4 rows of 16
#pragma unroll
    for (int r = 0; r < 4; ++r)
#pragma unroll
        for (int q = 0; q < 4; ++q) {
            float4 v = *(const float4*)(pr + r * 16 + q * 4);
            p[q * 4 + 0] += v.x; p[q * 4 + 1] += v.y;
            p[q * 4 + 2] += v.z; p[q * 4 + 3] += v.w;
        }
#pragma unroll
    for (int e = 0; e < NE; ++e) WSUM(p[e]);
    int w = tid >> 6, l = tid & 63;
    if (l == 0) {
#pragma unroll
        for (int e = 0; e < NE; ++e) wsum[w][e] = p[e];
    }
    __syncthreads();
    if (tid == 0) {
        const int* cnt = (const int*)(ws + WS_CNT);
        float s = 0.f;
#pragma unroll
        for (int e = 0; e < NE; ++e) {
            float sp = wsum[0][e] + wsum[1][e] + wsum[2][e] + wsum[3][e];
            s += sp * (float)cnt[e];
        }
        out[(size_t)NTOK * DMODEL] = (float)NE * s / ((float)NTOK * (float)NTOK);
    }
}

extern "C" void kernel_launch(void* const* d_in, const int* in_sizes, int n_in,
                              void* d_out, int out_size, void* d_ws, size_t ws_size,
                              hipStream_t stream) {
    const float* x          = (const float*)d_in[0];
    const float* w_down     = (const float*)d_in[1];
    const float* pos_embed  = (const float*)d_in[2];
    const float* gp_w       = (const float*)d_in[3];
    const float* gp_b       = (const float*)d_in[4];
    const float* attn_in_w  = (const float*)d_in[5];
    const float* attn_in_b  = (const float*)d_in[6];
    const float* attn_out_w = (const float*)d_in[7];
    const float* attn_out_b = (const float*)d_in[8];
    const float* ln_w       = (const float*)d_in[9];
    const float* ln_b       = (const float*)d_in[10];
    const float* ls_w       = (const float*)d_in[11];
    const float* ls_b       = (const float*)d_in[12];
    const float* g1_w       = (const float*)d_in[13];
    const float* g1_b       = (const float*)d_in[14];
    const float* g2_w       = (const float*)d_in[15];
    const float* g2_b       = (const float*)d_in[16];
    const float* w_up       = (const float*)d_in[17];
    float* ws  = (float*)d_ws;
    float* out = (float*)d_out;

    k_prep<<<dim3(512, 2), 256, 0, stream>>>(x, w_down, ws);
    k_batch_partial<<<32, 256, 0, stream>>>(x, ws);
    k_global_ctx<<<NB, 256, 0, stream>>>(gp_w, gp_b, g1_w, g1_b, g2_w, g2_b, ws);
    k_ef_mfma<<<dim3(16, 16, 2), 256, 0, stream>>>(ws);
    k_ef_combine<<<1024, 256, 0, stream>>>(ws);
    k_prep_wup<<<dim3(16, 16), 256, 0, stream>>>(w_up, ws);
    k_prep_attnw<<<1, 256, 0, stream>>>(attn_in_w, attn_out_w, ws);
    k_attn2<<<NTOK, 128, 0, stream>>>(pos_embed, attn_in_b, attn_out_b,
                                      ln_w, ln_b, ls_w, ls_b, ws);
    k_moe_gemm<<<dim3(NE, 16), 256, 0, stream>>>(ws);
    k_combine<<<NTOK, 256, 0, stream>>>(ws, out);
    k_aux<<<1, 256, 0, stream>>>(ws, out);
}

// Round 5
// 218.540 us; speedup vs baseline: 1.2259x; 1.0227x over previous
//
#include <hip/hip_runtime.h>
#include <math.h>

// Problem constants
#define NB 4
#define TT 256
#define DMODEL 1024
#define NE 16
#define DLQ 64
#define NH 4
#define HD 16
#define SEQL 17
#define NTOK 1024   // NB*TT

// Workspace layout (float offsets). Overlays by phase:
//   AH/AL/BH/BL + P1 die after k_ef_combine; ACT overlays AH (written by
//   k_attn2, after GEMM); WUPT overlays P1 (written by k_prep_wup, after
//   combine). Footprint end = 4,227,392 floats (proven budget).
static constexpr size_t WS_EF    = 0;          // 1024x1024 fp32 ef
static constexpr size_t WS_AH    = 1048576;    // x hi bf16 plane, frag-swizzled
static constexpr size_t WS_ACT   = 1048576;    // act bf16 [2048][64] (late, overlays AH)
static constexpr size_t WS_AL    = 1572864;    // x lo
static constexpr size_t WS_BH    = 2097152;    // w_down hi
static constexpr size_t WS_BL    = 2621440;    // w_down lo
static constexpr size_t WS_P1    = 3145728;    // K-split partial (1M floats)
static constexpr size_t WS_WUPT  = 3145728;    // w_up^T bf16 [16][1024][64] (late)
static constexpr size_t WS_CNT   = 3670016;    // 16 int expert counters
static constexpr size_t WS_LIST  = 3670032;    // 16x1024 int packed (tok*2+slot)
static constexpr size_t WS_AIWFH = 3702800;    // attn_in_w hi frags  (12288 sh)
static constexpr size_t WS_AIWFL = 3708944;    // attn_in_w lo frags
static constexpr size_t WS_AOWFH = 3715088;    // attn_out_w hi frags (4096 sh)
static constexpr size_t WS_AOWFL = 3717136;    // attn_out_w lo frags
static constexpr size_t WS_XPART = 4194304;    // 32x1024 batch partials (early)
static constexpr size_t WS_PR    = 4194304;    // 1024x16 probs (late, overlays XPART)
static constexpr size_t WS_GCTX  = 4227072;    // 4x64
static constexpr size_t WS_GB    = 4227328;    // 4x16

typedef __attribute__((ext_vector_type(8))) short short8;
typedef __attribute__((ext_vector_type(4))) float f32x4;

__device__ __forceinline__ float gelu_exact(float x) {
    return 0.5f * x * (1.0f + erff(x * 0.70710678118654752f));
}

__device__ __forceinline__ unsigned short f2bf(float f) {
    unsigned int u = __float_as_uint(f);
    unsigned int r = (u + 0x7fffu + ((u >> 16) & 1u)) >> 16;
    return (unsigned short)r;
}
__device__ __forceinline__ float bf2f(unsigned short h) {
    return __uint_as_float(((unsigned int)h) << 16);
}

// DPP row_ror all-reduce within 16-lane rows: VALU pipe, zero LDS ops.
#define DPP_ADD(v, ctrl) { int _m = __builtin_amdgcn_update_dpp(0, __float_as_int(v), ctrl, 0xF, 0xF, true); \
                           v += __int_as_float(_m); }
__device__ __forceinline__ float rsum16(float v) {
    DPP_ADD(v, 0x128);  // row_ror:8
    DPP_ADD(v, 0x124);  // row_ror:4
    DPP_ADD(v, 0x122);  // row_ror:2
    DPP_ADD(v, 0x121);  // row_ror:1
    return v;
}
__device__ __forceinline__ float rsum64(float v) {
    v = rsum16(v);
    v += __shfl_xor(v, 16);
    v += __shfl_xor(v, 32);
    return v;
}

// K0: split x / w_down into hi/lo bf16 planes, frag-swizzled (see round 4).
__global__ __launch_bounds__(256) void k_prep(const float* __restrict__ x,
                                              const float* __restrict__ wdn,
                                              float* __restrict__ ws) {
    int t = blockIdx.x * 256 + threadIdx.x;
    int row = t >> 7;
    int col0 = (t & 127) * 8;
    const float* src = blockIdx.y ? wdn : x;
    unsigned short* hp = (unsigned short*)(ws + (blockIdx.y ? WS_BH : WS_AH));
    unsigned short* lp = (unsigned short*)(ws + (blockIdx.y ? WS_BL : WS_AL));
    float4 v0 = *(const float4*)(src + (size_t)row * DMODEL + col0);
    float4 v1 = *(const float4*)(src + (size_t)row * DMODEL + col0 + 4);
    float vv[8] = {v0.x, v0.y, v0.z, v0.w, v1.x, v1.y, v1.z, v1.w};
    unsigned short h8[8], l8[8];
#pragma unroll
    for (int j = 0; j < 8; ++j) {
        h8[j] = f2bf(vv[j]);
        l8[j] = f2bf(vv[j] - bf2f(h8[j]));
    }
    int nb = row >> 6, kb = col0 >> 6;
    int st = (row & 63) >> 4;
    int ks = (col0 & 63) >> 5;
    int ln = (row & 15) + (((col0 >> 3) & 3) << 4);
    size_t off = (size_t)(nb * 16 + kb) * 4096 + st * 1024 + ks * 512 + ln * 8;
    *(short8*)(hp + off) = *(short8*)h8;
    *(short8*)(lp + off) = *(short8*)l8;
}

// K1a: per-(batch, slice) column sums of x
__global__ __launch_bounds__(256) void k_batch_partial(const float* __restrict__ x,
                                                       float* __restrict__ ws) {
    int b = blockIdx.x >> 3;
    int g = blockIdx.x & 7;
    int tid = threadIdx.x;
    const float* xp = x + (size_t)b * TT * DMODEL + (size_t)g * 32 * DMODEL + tid * 4;
    float4 acc = {0.f, 0.f, 0.f, 0.f};
#pragma unroll 4
    for (int t = 0; t < 32; ++t) {
        float4 v = *(const float4*)(xp + (size_t)t * DMODEL);
        acc.x += v.x; acc.y += v.y; acc.z += v.z; acc.w += v.w;
    }
    *(float4*)(ws + WS_XPART + (size_t)blockIdx.x * DMODEL + tid * 4) = acc;
}

// K1b: per batch: xmean -> gctx -> gelu MLP -> gb
__global__ __launch_bounds__(256) void k_global_ctx(const float* __restrict__ gp_w,
                                                    const float* __restrict__ gp_b,
                                                    const float* __restrict__ g1_w,
                                                    const float* __restrict__ g1_b,
                                                    const float* __restrict__ g2_w,
                                                    const float* __restrict__ g2_b,
                                                    float* __restrict__ ws) {
    int b = blockIdx.x, tid = threadIdx.x;
    __shared__ float xm[DMODEL];
    __shared__ float gc[DLQ];
    __shared__ float gb1[128];
    float4 a = {0.f, 0.f, 0.f, 0.f};
#pragma unroll
    for (int g = 0; g < 8; ++g) {
        float4 v = *(const float4*)(ws + WS_XPART + (size_t)(b * 8 + g) * DMODEL + tid * 4);
        a.x += v.x; a.y += v.y; a.z += v.z; a.w += v.w;
    }
    const float inv_t = 1.0f / (float)TT;
    xm[tid * 4 + 0] = a.x * inv_t;
    xm[tid * 4 + 1] = a.y * inv_t;
    xm[tid * 4 + 2] = a.z * inv_t;
    xm[tid * 4 + 3] = a.w * inv_t;
    __syncthreads();
    if (tid < DLQ) {
        const float* wr = gp_w + (size_t)tid * DMODEL;
        float s = 0.f;
        for (int j = 0; j < DMODEL; j += 4) {
            float4 w4 = *(const float4*)(wr + j);
            float4 x4 = *(const float4*)&xm[j];
            s += w4.x * x4.x + w4.y * x4.y + w4.z * x4.z + w4.w * x4.w;
        }
        float v = s + gp_b[tid];
        gc[tid] = v;
        ws[WS_GCTX + b * DLQ + tid] = v;
    }
    __syncthreads();
    if (tid < 128) {
        const float* wr = g1_w + (size_t)tid * DLQ;
        float s = 0.f;
        for (int j = 0; j < DLQ; j += 4) {
            float4 w4 = *(const float4*)(wr + j);
            float4 x4 = *(const float4*)&gc[j];
            s += w4.x * x4.x + w4.y * x4.y + w4.z * x4.z + w4.w * x4.w;
        }
        gb1[tid] = gelu_exact(s + g1_b[tid]);
    }
    __syncthreads();
    if (tid < NE) {
        const float* wr = g2_w + (size_t)tid * 128;
        float s = 0.f;
        for (int j = 0; j < 128; ++j) s += wr[j] * gb1[j];
        ws[WS_GB + b * NE + tid] = s + g2_b[tid];
    }
}

// K2: ef GEMM. 64x64 tile, K split over 2 blocks, BK=64, 3-term hi/lo bf16.
__global__ __launch_bounds__(256) void k_ef_mfma(float* __restrict__ ws) {
    __shared__ __attribute__((aligned(16))) unsigned short smem[16384];
    const unsigned short* AhP = (const unsigned short*)(ws + WS_AH);
    const unsigned short* AlP = (const unsigned short*)(ws + WS_AL);
    const unsigned short* BhP = (const unsigned short*)(ws + WS_BH);
    const unsigned short* BlP = (const unsigned short*)(ws + WS_BL);
    int tid = threadIdx.x;
    int mb = blockIdx.x;
    int nb = blockIdx.y;
    int kz = blockIdx.z;
    int w = tid >> 6, l = tid & 63;
    int wn = (w >> 1) * 32, wm = (w & 1) * 32;
    int stA = wn >> 4, stB = wm >> 4;
    f32x4 acc00 = {0.f, 0.f, 0.f, 0.f}, acc01 = acc00, acc10 = acc00, acc11 = acc00;

    for (int it = 0; it < 8; ++it) {
        int kb = kz * 8 + it;
        const char* srcs[4] = {
            (const char*)(AhP + (size_t)(nb * 16 + kb) * 4096),
            (const char*)(AlP + (size_t)(nb * 16 + kb) * 4096),
            (const char*)(BhP + (size_t)(mb * 16 + kb) * 4096),
            (const char*)(BlP + (size_t)(mb * 16 + kb) * 4096)};
#pragma unroll
        for (int p = 0; p < 4; ++p) {
#pragma unroll
            for (int h = 0; h < 2; ++h) {
                __builtin_amdgcn_global_load_lds(
                    (const __attribute__((address_space(1))) void*)(srcs[p] + h * 4096 + tid * 16),
                    (__attribute__((address_space(3))) void*)((char*)smem + p * 8192 + h * 4096 + tid * 16),
                    16, 0, 0);
            }
        }
        __syncthreads();
        const unsigned short* Ah = smem;
        const unsigned short* Al = smem + 4096;
        const unsigned short* Bh = smem + 8192;
        const unsigned short* Bl = smem + 12288;
#pragma unroll
        for (int ks = 0; ks < 2; ++ks) {
            short8 ah0 = *(const short8*)(Ah + (stA + 0) * 1024 + ks * 512 + l * 8);
            short8 ah1 = *(const short8*)(Ah + (stA + 1) * 1024 + ks * 512 + l * 8);
            short8 al0 = *(const short8*)(Al + (stA + 0) * 1024 + ks * 512 + l * 8);
            short8 al1 = *(const short8*)(Al + (stA + 1) * 1024 + ks * 512 + l * 8);
            short8 bh0 = *(const short8*)(Bh + (stB + 0) * 1024 + ks * 512 + l * 8);
            short8 bh1 = *(const short8*)(Bh + (stB + 1) * 1024 + ks * 512 + l * 8);
            short8 bl0 = *(const short8*)(Bl + (stB + 0) * 1024 + ks * 512 + l * 8);
            short8 bl1 = *(const short8*)(Bl + (stB + 1) * 1024 + ks * 512 + l * 8);
            acc00 = __builtin_amdgcn_mfma_f32_16x16x32_bf16(ah0, bh0, acc00, 0, 0, 0);
            acc00 = __builtin_amdgcn_mfma_f32_16x16x32_bf16(al0, bh0, acc00, 0, 0, 0);
            acc00 = __builtin_amdgcn_mfma_f32_16x16x32_bf16(ah0, bl0, acc00, 0, 0, 0);
            acc01 = __builtin_amdgcn_mfma_f32_16x16x32_bf16(ah0, bh1, acc01, 0, 0, 0);
            acc01 = __builtin_amdgcn_mfma_f32_16x16x32_bf16(al0, bh1, acc01, 0, 0, 0);
            acc01 = __builtin_amdgcn_mfma_f32_16x16x32_bf16(ah0, bl1, acc01, 0, 0, 0);
            acc10 = __builtin_amdgcn_mfma_f32_16x16x32_bf16(ah1, bh0, acc10, 0, 0, 0);
            acc10 = __builtin_amdgcn_mfma_f32_16x16x32_bf16(al1, bh0, acc10, 0, 0, 0);
            acc10 = __builtin_amdgcn_mfma_f32_16x16x32_bf16(ah1, bl0, acc10, 0, 0, 0);
            acc11 = __builtin_amdgcn_mfma_f32_16x16x32_bf16(ah1, bh1, acc11, 0, 0, 0);
            acc11 = __builtin_amdgcn_mfma_f32_16x16x32_bf16(al1, bh1, acc11, 0, 0, 0);
            acc11 = __builtin_amdgcn_mfma_f32_16x16x32_bf16(ah1, bl1, acc11, 0, 0, 0);
        }
        __syncthreads();
    }
    int cr = (l >> 4) * 4, cc = l & 15;
    int n0 = nb * 64, m0 = mb * 64;
    float* P = ws + (kz == 0 ? WS_EF : WS_P1);
#pragma unroll
    for (int r = 0; r < 4; ++r) {
        P[(size_t)(n0 + wn + cr + r) * DMODEL + (m0 + wm + cc)]           = acc00[r];
        P[(size_t)(n0 + wn + cr + r) * DMODEL + (m0 + wm + 16 + cc)]      = acc01[r];
        P[(size_t)(n0 + wn + 16 + cr + r) * DMODEL + (m0 + wm + cc)]      = acc10[r];
        P[(size_t)(n0 + wn + 16 + cr + r) * DMODEL + (m0 + wm + 16 + cc)] = acc11[r];
    }
}

// K2c: EF += P1
__global__ __launch_bounds__(256) void k_ef_combine(float* __restrict__ ws) {
    size_t i = ((size_t)blockIdx.x * 256 + threadIdx.x) * 4;
    float4 a = *(const float4*)(ws + WS_EF + i);
    float4 b = *(const float4*)(ws + WS_P1 + i);
    float4 o = {a.x + b.x, a.y + b.y, a.z + b.z, a.w + b.w};
    *(float4*)(ws + WS_EF + i) = o;
}

// K2b: transpose w_up -> bf16 w_up^T; zero counters; blocks (0,1)/(0,2) also
// build the attn weight frag planes (merged former k_prep_attnw).
__global__ __launch_bounds__(256) void k_prep_wup(const float* __restrict__ w_up,
                                                  const float* __restrict__ aiw,
                                                  const float* __restrict__ aow,
                                                  float* __restrict__ ws) {
    int e = blockIdx.x, ct = blockIdx.y, tid = threadIdx.x;
    __shared__ float tile[64][65];
#pragma unroll
    for (int jj = 0; jj < 16; ++jj) {
        int j = jj * 4 + (tid >> 6);
        tile[j][tid & 63] = w_up[((size_t)e * DLQ + j) * DMODEL + ct * 64 + (tid & 63)];
    }
    if (e == 0 && ct == 0 && tid < 16) ((int*)(ws + WS_CNT))[tid] = 0;
    __syncthreads();
    int c = tid >> 2, j0 = (tid & 3) * 16;
    unsigned short* dst = (unsigned short*)(ws + WS_WUPT) +
                          (size_t)e * 65536 + (size_t)(ct * 64 + c) * 64 + j0;
#pragma unroll
    for (int q = 0; q < 4; ++q) {
        ushort4 o;
        o.x = f2bf(tile[j0 + q * 4 + 0][c]);
        o.y = f2bf(tile[j0 + q * 4 + 1][c]);
        o.z = f2bf(tile[j0 + q * 4 + 2][c]);
        o.w = f2bf(tile[j0 + q * 4 + 3][c]);
        *(ushort4*)(dst + q * 4) = o;
    }
    if (e == 0 && ct == 1) {
        unsigned short* fh = (unsigned short*)(ws + WS_AIWFH);
        unsigned short* fl = (unsigned short*)(ws + WS_AIWFL);
        for (int idx = tid; idx < 12 * 2 * 64; idx += 256) {
            int nt = idx >> 7, kf = (idx >> 6) & 1, l = idx & 63;
            int row = nt * 16 + (l & 15);
            int k = kf * 32 + ((l >> 4) << 3);
            const float* src = aiw + (size_t)row * DLQ + k;
            unsigned short h8[8], l8[8];
#pragma unroll
            for (int j = 0; j < 8; ++j) {
                h8[j] = f2bf(src[j]);
                l8[j] = f2bf(src[j] - bf2f(h8[j]));
            }
            size_t off = (size_t)(nt * 2 + kf) * 512 + l * 8;
            *(short8*)(fh + off) = *(short8*)h8;
            *(short8*)(fl + off) = *(short8*)l8;
        }
    }
    if (e == 0 && ct == 2) {
        unsigned short* gh = (unsigned short*)(ws + WS_AOWFH);
        unsigned short* gl = (unsigned short*)(ws + WS_AOWFL);
        for (int idx = tid; idx < 4 * 2 * 64; idx += 256) {
            int nt = idx >> 7, kf = (idx >> 6) & 1, l = idx & 63;
            int row = nt * 16 + (l & 15);
            int k = kf * 32 + ((l >> 4) << 3);
            const float* src = aow + (size_t)row * DLQ + k;
            unsigned short h8[8], l8[8];
#pragma unroll
            for (int j = 0; j < 8; ++j) {
                h8[j] = f2bf(src[j]);
                l8[j] = f2bf(src[j] - bf2f(h8[j]));
            }
            size_t off = (size_t)(nt * 2 + kf) * 512 + l * 8;
            *(short8*)(gh + off) = *(short8*)h8;
            *(short8*)(gl + off) = *(short8*)l8;
        }
    }
}

// K3: one token per block (2 waves). MFMA qkv/attn_out, DPP-reduce scores,
// split LN/logits across waves, routing + ACT epilogue.
__global__ __launch_bounds__(128) void k_attn2(const float* __restrict__ pos_embed,
                                               const float* __restrict__ attn_in_b,
                                               const float* __restrict__ attn_out_b,
                                               const float* __restrict__ ln_w,
                                               const float* __restrict__ ln_b,
                                               const float* __restrict__ ls_w,
                                               const float* __restrict__ ls_b,
                                               float* __restrict__ ws) {
    int n = blockIdx.x;
    int w = threadIdx.x >> 6;
    int l = threadIdx.x & 63;
    int b = n >> 8;

    __shared__ float qkv[SEQL * 200];
    __shared__ __attribute__((aligned(16))) char ubuf[8192];   // sH/sL then ao
    __shared__ __attribute__((aligned(16))) unsigned short ctxH[1024];
    __shared__ __attribute__((aligned(16))) unsigned short ctxL[1024];
    __shared__ float lgv_sh[NE];
    unsigned short* sH = (unsigned short*)ubuf;
    unsigned short* sL = (unsigned short*)(ubuf + 4096);
    float* ao = (float*)ubuf;

    // Phase 1: seq column l in regs; hi/lo frag-linear LDS
    float seqc[SEQL];
    {
        const float* efp = ws + WS_EF + (size_t)n * DMODEL;
        float gcv = ws[WS_GCTX + b * DLQ + l];
#pragma unroll
        for (int i = 0; i < SEQL; ++i) {
            float s = (i == 0) ? gcv : efp[(i - 1) * DLQ + l] + pos_embed[(i - 1) * DLQ + l];
            seqc[i] = s;
            int lo_r = w * 9, hi_r = w * 9 + 8;
            if (i >= lo_r && i <= hi_r && i < SEQL) {
                unsigned short hs = f2bf(s);
                unsigned short lsv = f2bf(s - bf2f(hs));
                int mt = i >> 4;
                int ls = (i & 15) + (((l >> 3) & 3) << 4);
                int kf = l >> 5;
                int j = l & 7;
                size_t off = (size_t)(mt * 2 + kf) * 512 + ls * 8 + j;
                sH[off] = hs;
                sL[off] = lsv;
            }
        }
    }
    __syncthreads();

    // Phase 2: qkv = seq @ aiw^T via MFMA (wave w: N-tiles w*6..w*6+5)
    {
        const unsigned short* fh = (const unsigned short*)(ws + WS_AIWFH);
        const unsigned short* fl = (const unsigned short*)(ws + WS_AIWFL);
        f32x4 acc[6][2];
#pragma unroll
        for (int t = 0; t < 6; ++t)
#pragma unroll
            for (int m = 0; m < 2; ++m) acc[t][m] = (f32x4){0.f, 0.f, 0.f, 0.f};
#pragma unroll
        for (int kf = 0; kf < 2; ++kf) {
            short8 ah0 = *(const short8*)(sH + (0 * 2 + kf) * 512 + l * 8);
            short8 ah1 = *(const short8*)(sH + (1 * 2 + kf) * 512 + l * 8);
            short8 al0 = *(const short8*)(sL + (0 * 2 + kf) * 512 + l * 8);
            short8 al1 = *(const short8*)(sL + (1 * 2 + kf) * 512 + l * 8);
#pragma unroll
            for (int t = 0; t < 6; ++t) {
                int nt = w * 6 + t;
                short8 bh = *(const short8*)(fh + (size_t)(nt * 2 + kf) * 512 + l * 8);
                short8 bl = *(const short8*)(fl + (size_t)(nt * 2 + kf) * 512 + l * 8);
                acc[t][0] = __builtin_amdgcn_mfma_f32_16x16x32_bf16(ah0, bh, acc[t][0], 0, 0, 0);
                acc[t][0] = __builtin_amdgcn_mfma_f32_16x16x32_bf16(al0, bh, acc[t][0], 0, 0, 0);
                acc[t][0] = __builtin_amdgcn_mfma_f32_16x16x32_bf16(ah0, bl, acc[t][0], 0, 0, 0);
                acc[t][1] = __builtin_amdgcn_mfma_f32_16x16x32_bf16(ah1, bh, acc[t][1], 0, 0, 0);
                acc[t][1] = __builtin_amdgcn_mfma_f32_16x16x32_bf16(al1, bh, acc[t][1], 0, 0, 0);
                acc[t][1] = __builtin_amdgcn_mfma_f32_16x16x32_bf16(ah1, bl, acc[t][1], 0, 0, 0);
            }
        }
#pragma unroll
        for (int t = 0; t < 6; ++t) {
            int col = (w * 6 + t) * 16 + (l & 15);
            float bias = attn_in_b[col];
#pragma unroll
            for (int r = 0; r < 4; ++r) {
                int row = (l >> 4) * 4 + r;
                qkv[row * 200 + col] = acc[t][0][r] + bias;
            }
            if ((l >> 4) == 0) qkv[16 * 200 + col] = acc[t][1][0] + bias;
        }
    }
    __syncthreads();

    // Phase 3: scores via DPP 16-lane reduce (head g=l>>4), lane-local softmax, ctx.
    {
        int g = l >> 4;
        float kc[SEQL], vc[SEQL];
#pragma unroll
        for (int j = 0; j < SEQL; ++j) {
            kc[j] = qkv[j * 200 + 64 + g * 16 + (l & 15)];
            vc[j] = qkv[j * 200 + 128 + l];
        }
        for (int i = w * 8 + 1; i <= w * 8 + 8; ++i) {
            float qi = qkv[i * 200 + g * 16 + (l & 15)];
            float sj[SEQL];
#pragma unroll
            for (int j = 0; j < SEQL; ++j) {
                sj[j] = rsum16(qi * kc[j]) * 0.25f;
            }
            float m = sj[0];
#pragma unroll
            for (int j = 1; j < SEQL; ++j) m = fmaxf(m, sj[j]);
            float ssum = 0.f;
#pragma unroll
            for (int j = 0; j < SEQL; ++j) { sj[j] = __expf(sj[j] - m); ssum += sj[j]; }
            float inv = 1.f / ssum;
            float c = 0.f;
#pragma unroll
            for (int j = 0; j < SEQL; ++j) c += sj[j] * vc[j];
            c *= inv;
            unsigned short ch = f2bf(c);
            unsigned short cl = f2bf(c - bf2f(ch));
            int ls = ((i - 1) & 15) + (((l >> 3) & 3) << 4);
            int kf = l >> 5;
            int j2 = l & 7;
            size_t off = (size_t)kf * 512 + ls * 8 + j2;
            ctxH[off] = ch;
            ctxL[off] = cl;
        }
    }
    __syncthreads();

    // Phase 4: attn_out = ctx @ aow^T via MFMA (ao overlays sH/sL region)
    {
        const unsigned short* gh = (const unsigned short*)(ws + WS_AOWFH);
        const unsigned short* gl = (const unsigned short*)(ws + WS_AOWFL);
        f32x4 acc[2];
        acc[0] = (f32x4){0.f, 0.f, 0.f, 0.f};
        acc[1] = acc[0];
#pragma unroll
        for (int kf = 0; kf < 2; ++kf) {
            short8 ah = *(const short8*)(ctxH + kf * 512 + l * 8);
            short8 al = *(const short8*)(ctxL + kf * 512 + l * 8);
#pragma unroll
            for (int t = 0; t < 2; ++t) {
                int nt = w * 2 + t;
                short8 bh = *(const short8*)(gh + (size_t)(nt * 2 + kf) * 512 + l * 8);
                short8 bl = *(const short8*)(gl + (size_t)(nt * 2 + kf) * 512 + l * 8);
                acc[t] = __builtin_amdgcn_mfma_f32_16x16x32_bf16(ah, bh, acc[t], 0, 0, 0);
                acc[t] = __builtin_amdgcn_mfma_f32_16x16x32_bf16(al, bh, acc[t], 0, 0, 0);
                acc[t] = __builtin_amdgcn_mfma_f32_16x16x32_bf16(ah, bl, acc[t], 0, 0, 0);
            }
        }
        __syncthreads();   // everyone past P2 reads of sH/sL before ao overwrite
#pragma unroll
        for (int t = 0; t < 2; ++t) {
            int col = (w * 2 + t) * 16 + (l & 15);
            float bias = attn_out_b[col];
#pragma unroll
            for (int r = 0; r < 4; ++r) {
                int row = (l >> 4) * 4 + r;
                ao[row * 72 + col] = acc[t][r] + bias;
            }
        }
    }
    __syncthreads();

    // Phase 5: residual + LN + logits (split: wave w handles e = w*8..w*8+7)
    float rs[SEQL];
#pragma unroll
    for (int i = 1; i < SEQL; ++i) rs[i] = seqc[i] + ao[(i - 1) * 72 + l];

    float c1 = ln_w[l] * ls_w[l];
    float c1sum = rsum64(c1);
    float c0sum = rsum64(ln_b[l] * ls_w[l]);
    float lsb0 = ls_b[0];
#pragma unroll
    for (int ee = 0; ee < 8; ++ee) {
        int e = w * 8 + ee;
        float x = rs[e + 1];
        float s1 = rsum64(x);
        float s2 = rsum64(x * x);
        float s3 = rsum64(x * c1);
        float mu = s1 * (1.0f / DLQ);
        float var = s2 * (1.0f / DLQ) - mu * mu;
        float rstd = rsqrtf(var + 1e-5f);
        float lgv = rstd * (s3 - mu * c1sum) + c0sum + lsb0 + ws[WS_GB + b * NE + e];
        if (l == 0) lgv_sh[e] = lgv;
    }
    __syncthreads();

    // softmax + top2 (redundant across lanes; only w0 commits)
    float p[NE];
    {
        float lgv[NE];
#pragma unroll
        for (int e = 0; e < NE; ++e) lgv[e] = lgv_sh[e];
        float m = lgv[0];
#pragma unroll
        for (int e = 1; e < NE; ++e) m = fmaxf(m, lgv[e]);
        float ssum = 0.f;
#pragma unroll
        for (int e = 0; e < NE; ++e) { p[e] = __expf(lgv[e] - m); ssum += p[e]; }
        float inv = 1.f / ssum;
#pragma unroll
        for (int e = 0; e < NE; ++e) p[e] *= inv;
    }
    int t0 = 0; float b0 = p[0];
#pragma unroll
    for (int e = 1; e < NE; ++e) if (p[e] > b0) { b0 = p[e]; t0 = e; }
    int t1 = -1; float b1 = -1.f;
#pragma unroll
    for (int e = 0; e < NE; ++e) if (e != t0 && p[e] > b1) { b1 = p[e]; t1 = e; }

    if (w == 0) {
        float sw = b0 + b1;
        float tw0 = b0 / sw, tw1 = b1 / sw;
        // ACT epilogue: gelu(raw ef of selected experts) * weight, bf16
        unsigned short* actp = (unsigned short*)(ws + WS_ACT);
        float efv0 = ws[WS_EF + (size_t)n * DMODEL + t0 * DLQ + l];
        float efv1 = ws[WS_EF + (size_t)n * DMODEL + t1 * DLQ + l];
        actp[(size_t)(n * 2 + 0) * 64 + l] = f2bf(gelu_exact(efv0) * tw0);
        actp[(size_t)(n * 2 + 1) * 64 + l] = f2bf(gelu_exact(efv1) * tw1);
        if (l == 0) {
#pragma unroll
            for (int e = 0; e < NE; ++e) ws[WS_PR + (size_t)n * NE + e] = p[e];
            int* cnt  = (int*)(ws + WS_CNT);
            int* list = (int*)(ws + WS_LIST);
            int i0 = atomicAdd(&cnt[t0], 1);
            list[t0 * 1024 + i0] = n * 2;
            int i1 = atomicAdd(&cnt[t1], 1);
            list[t1 * 1024 + i1] = n * 2 + 1;
        }
    }
}

// K4: expert-major MoE GEMM, barrier-free. Block = (e, 64-col tile), 4 waves.
// A-frags gathered per-lane from ACT; accumulate into out via atomicAdd
// (exactly 2 commutative adds per element onto memset-zeroed out).
__global__ __launch_bounds__(256) void k_moe_gemm(float* __restrict__ ws,
                                                  float* __restrict__ out) {
    int e = blockIdx.x, ct = blockIdx.y;
    int cnt = ((const int*)(ws + WS_CNT))[e];
    if (cnt == 0) return;
    int wv = threadIdx.x >> 6, l = threadIdx.x & 63;
    const int* list = (const int*)(ws + WS_LIST) + e * 1024;
    const unsigned short* wupt = (const unsigned short*)(ws + WS_WUPT) + (size_t)e * 65536;
    const unsigned short* actp = (const unsigned short*)(ws + WS_ACT);
    int col = ct * 64 + wv * 16 + (l & 15);
    int kb = (l >> 4) * 8;
    short8 bf0 = *(const short8*)(wupt + (size_t)col * 64 + kb);
    short8 bf1 = *(const short8*)(wupt + (size_t)col * 64 + 32 + kb);
    int cr = (l >> 4) * 4;

    for (int mt = 0; mt < cnt; mt += 16) {
        int row = mt + (l & 15);
        short8 a0 = {0, 0, 0, 0, 0, 0, 0, 0};
        short8 a1 = {0, 0, 0, 0, 0, 0, 0, 0};
        if (row < cnt) {
            int pk = list[row];
            a0 = *(const short8*)(actp + (size_t)pk * 64 + kb);
            a1 = *(const short8*)(actp + (size_t)pk * 64 + 32 + kb);
        }
        f32x4 acc = {0.f, 0.f, 0.f, 0.f};
        acc = __builtin_amdgcn_mfma_f32_16x16x32_bf16(a0, bf0, acc, 0, 0, 0);
        acc = __builtin_amdgcn_mfma_f32_16x16x32_bf16(a1, bf1, acc, 0, 0, 0);
#pragma unroll
        for (int r = 0; r < 4; ++r) {
            int rr = mt + cr + r;
            if (rr < cnt) {
                int pk = list[rr];
                atomicAdd(&out[(size_t)(pk >> 1) * DMODEL + col], acc[r]);
            }
        }
    }
}

// K6: aux loss from probs + expert counters
__global__ __launch_bounds__(256) void k_aux(const float* __restrict__ ws, float* __restrict__ out) {
    int tid = threadIdx.x;
    __shared__ float wsum[4][NE];
    float p[NE];
#pragma unroll
    for (int e = 0; e < NE; ++e) p[e] = 0.f;
    const float* pr = ws + WS_PR + (size_t)tid * 64;
#pragma unroll
    for (int r = 0; r < 4; ++r)
#pragma unroll
        for (int q = 0; q < 4; ++q) {
            float4 v = *(const float4*)(pr + r * 16 + q * 4);
            p[q * 4 + 0] += v.x; p[q * 4 + 1] += v.y;
            p[q * 4 + 2] += v.z; p[q * 4 + 3] += v.w;
        }
#pragma unroll
    for (int e = 0; e < NE; ++e) p[e] = rsum64(p[e]);
    int w = tid >> 6, l = tid & 63;
    if (l == 0) {
#pragma unroll
        for (int e = 0; e < NE; ++e) wsum[w][e] = p[e];
    }
    __syncthreads();
    if (tid == 0) {
        const int* cnt = (const int*)(ws + WS_CNT);
        float s = 0.f;
#pragma unroll
        for (int e = 0; e < NE; ++e) {
            float sp = wsum[0][e] + wsum[1][e] + wsum[2][e] + wsum[3][e];
            s += sp * (float)cnt[e];
        }
        out[(size_t)NTOK * DMODEL] = (float)NE * s / ((float)NTOK * (float)NTOK);
    }
}

extern "C" void kernel_launch(void* const* d_in, const int* in_sizes, int n_in,
                              void* d_out, int out_size, void* d_ws, size_t ws_size,
                              hipStream_t stream) {
    const float* x          = (const float*)d_in[0];
    const float* w_down     = (const float*)d_in[1];
    const float* pos_embed  = (const float*)d_in[2];
    const float* gp_w       = (const float*)d_in[3];
    const float* gp_b       = (const float*)d_in[4];
    const float* attn_in_w  = (const float*)d_in[5];
    const float* attn_in_b  = (const float*)d_in[6];
    const float* attn_out_w = (const float*)d_in[7];
    const float* attn_out_b = (const float*)d_in[8];
    const float* ln_w       = (const float*)d_in[9];
    const float* ln_b       = (const float*)d_in[10];
    const float* ls_w       = (const float*)d_in[11];
    const float* ls_b       = (const float*)d_in[12];
    const float* g1_w       = (const float*)d_in[13];
    const float* g1_b       = (const float*)d_in[14];
    const float* g2_w       = (const float*)d_in[15];
    const float* g2_b       = (const float*)d_in[16];
    const float* w_up       = (const float*)d_in[17];
    float* ws  = (float*)d_ws;
    float* out = (float*)d_out;

    hipMemsetAsync(out, 0, (size_t)out_size * sizeof(float), stream);
    k_prep<<<dim3(512, 2), 256, 0, stream>>>(x, w_down, ws);
    k_batch_partial<<<32, 256, 0, stream>>>(x, ws);
    k_global_ctx<<<NB, 256, 0, stream>>>(gp_w, gp_b, g1_w, g1_b, g2_w, g2_b, ws);
    k_ef_mfma<<<dim3(16, 16, 2), 256, 0, stream>>>(ws);
    k_ef_combine<<<1024, 256, 0, stream>>>(ws);
    k_prep_wup<<<dim3(16, 16), 256, 0, stream>>>(w_up, attn_in_w, attn_out_w, ws);
    k_attn2<<<NTOK, 128, 0, stream>>>(pos_embed, attn_in_b, attn_out_b,
                                      ln_w, ln_b, ls_w, ls_b, ws);
    k_moe_gemm<<<dim3(NE, 16), 256, 0, stream>>>(ws, out);
    k_aux<<<1, 256, 0, stream>>>(ws, out);
}

// Round 7
// 184.180 us; speedup vs baseline: 1.4545x; 1.1866x over previous
//
#include <hip/hip_runtime.h>
#include <math.h>

// Problem constants
#define NB 4
#define TT 256
#define DMODEL 1024
#define NE 16
#define DLQ 64
#define NH 4
#define HD 16
#define SEQL 17
#define NTOK 1024   // NB*TT

// Workspace layout (float offsets). Overlays:
//   AH/AL/BH/BL die after k_ef_mfma. ACT overlays AH (written by k_attn2).
//   WUPT overlays AL; attn frag planes overlay BH (both written by k_prep_wup
//   AFTER k_ef_mfma). P1 stays LIVE until k_attn2 completes — nothing may
//   overlay 3145728..4194304 before then (round-6 bug: frag planes did).
static constexpr size_t WS_EF    = 0;          // 1024x1024 fp32 ef partial P0
static constexpr size_t WS_AH    = 1048576;    // x hi bf16 plane, frag-swizzled
static constexpr size_t WS_ACT   = 1048576;    // act bf16 [2048][64] (late, overlays AH)
static constexpr size_t WS_AL    = 1572864;    // x lo
static constexpr size_t WS_WUPT  = 1572864;    // w_up^T bf16 [16][1024][64] (late, overlays AL)
static constexpr size_t WS_BH    = 2097152;    // w_down hi
static constexpr size_t WS_AIWFH = 2097152;    // attn_in_w hi frags  (12288 sh, overlays BH)
static constexpr size_t WS_AIWFL = 2103296;    // attn_in_w lo frags
static constexpr size_t WS_AOWFH = 2109440;    // attn_out_w hi frags (4096 sh)
static constexpr size_t WS_AOWFL = 2111488;    // attn_out_w lo frags
static constexpr size_t WS_BL    = 2621440;    // w_down lo
static constexpr size_t WS_P1    = 3145728;    // K-split partial P1 (LIVE until k_attn2 done)
static constexpr size_t WS_XPART = 4194304;    // 32x1024 batch partials (early)
static constexpr size_t WS_PR    = 4194304;    // 1024x16 probs (late, overlays XPART)
static constexpr size_t WS_TI    = 4210688;    // 1024 packed ints: t0 | t1<<8
static constexpr size_t WS_GCTX  = 4227072;    // 4x64
static constexpr size_t WS_GB    = 4227328;    // 4x16

typedef __attribute__((ext_vector_type(8))) short short8;
typedef __attribute__((ext_vector_type(4))) float f32x4;

__device__ __forceinline__ float gelu_exact(float x) {
    return 0.5f * x * (1.0f + erff(x * 0.70710678118654752f));
}

__device__ __forceinline__ unsigned short f2bf(float f) {
    unsigned int u = __float_as_uint(f);
    unsigned int r = (u + 0x7fffu + ((u >> 16) & 1u)) >> 16;
    return (unsigned short)r;
}
__device__ __forceinline__ float bf2f(unsigned short h) {
    return __uint_as_float(((unsigned int)h) << 16);
}

// DPP row_ror all-reduce within 16-lane rows: VALU pipe, zero LDS ops.
#define DPP_ADD(v, ctrl) { int _m = __builtin_amdgcn_update_dpp(0, __float_as_int(v), ctrl, 0xF, 0xF, true); \
                           v += __int_as_float(_m); }
__device__ __forceinline__ float rsum16(float v) {
    DPP_ADD(v, 0x128);  // row_ror:8
    DPP_ADD(v, 0x124);  // row_ror:4
    DPP_ADD(v, 0x122);  // row_ror:2
    DPP_ADD(v, 0x121);  // row_ror:1
    return v;
}
__device__ __forceinline__ float rsum64(float v) {
    v = rsum16(v);
    v += __shfl_xor(v, 16);
    v += __shfl_xor(v, 32);
    return v;
}

// K0: split x / w_down into hi/lo bf16 planes, frag-swizzled.
__global__ __launch_bounds__(256) void k_prep(const float* __restrict__ x,
                                              const float* __restrict__ wdn,
                                              float* __restrict__ ws) {
    int t = blockIdx.x * 256 + threadIdx.x;
    int row = t >> 7;
    int col0 = (t & 127) * 8;
    const float* src = blockIdx.y ? wdn : x;
    unsigned short* hp = (unsigned short*)(ws + (blockIdx.y ? WS_BH : WS_AH));
    unsigned short* lp = (unsigned short*)(ws + (blockIdx.y ? WS_BL : WS_AL));
    float4 v0 = *(const float4*)(src + (size_t)row * DMODEL + col0);
    float4 v1 = *(const float4*)(src + (size_t)row * DMODEL + col0 + 4);
    float vv[8] = {v0.x, v0.y, v0.z, v0.w, v1.x, v1.y, v1.z, v1.w};
    unsigned short h8[8], l8[8];
#pragma unroll
    for (int j = 0; j < 8; ++j) {
        h8[j] = f2bf(vv[j]);
        l8[j] = f2bf(vv[j] - bf2f(h8[j]));
    }
    int nb = row >> 6, kb = col0 >> 6;
    int st = (row & 63) >> 4;
    int ks = (col0 & 63) >> 5;
    int ln = (row & 15) + (((col0 >> 3) & 3) << 4);
    size_t off = (size_t)(nb * 16 + kb) * 4096 + st * 1024 + ks * 512 + ln * 8;
    *(short8*)(hp + off) = *(short8*)h8;
    *(short8*)(lp + off) = *(short8*)l8;
}

// K1a: per-(batch, slice) column sums of x
__global__ __launch_bounds__(256) void k_batch_partial(const float* __restrict__ x,
                                                       float* __restrict__ ws) {
    int b = blockIdx.x >> 3;
    int g = blockIdx.x & 7;
    int tid = threadIdx.x;
    const float* xp = x + (size_t)b * TT * DMODEL + (size_t)g * 32 * DMODEL + tid * 4;
    float4 acc = {0.f, 0.f, 0.f, 0.f};
#pragma unroll 4
    for (int t = 0; t < 32; ++t) {
        float4 v = *(const float4*)(xp + (size_t)t * DMODEL);
        acc.x += v.x; acc.y += v.y; acc.z += v.z; acc.w += v.w;
    }
    *(float4*)(ws + WS_XPART + (size_t)blockIdx.x * DMODEL + tid * 4) = acc;
}

// K1b: per batch: xmean -> gctx -> gelu MLP -> gb
__global__ __launch_bounds__(256) void k_global_ctx(const float* __restrict__ gp_w,
                                                    const float* __restrict__ gp_b,
                                                    const float* __restrict__ g1_w,
                                                    const float* __restrict__ g1_b,
                                                    const float* __restrict__ g2_w,
                                                    const float* __restrict__ g2_b,
                                                    float* __restrict__ ws) {
    int b = blockIdx.x, tid = threadIdx.x;
    __shared__ float xm[DMODEL];
    __shared__ float gc[DLQ];
    __shared__ float gb1[128];
    float4 a = {0.f, 0.f, 0.f, 0.f};
#pragma unroll
    for (int g = 0; g < 8; ++g) {
        float4 v = *(const float4*)(ws + WS_XPART + (size_t)(b * 8 + g) * DMODEL + tid * 4);
        a.x += v.x; a.y += v.y; a.z += v.z; a.w += v.w;
    }
    const float inv_t = 1.0f / (float)TT;
    xm[tid * 4 + 0] = a.x * inv_t;
    xm[tid * 4 + 1] = a.y * inv_t;
    xm[tid * 4 + 2] = a.z * inv_t;
    xm[tid * 4 + 3] = a.w * inv_t;
    __syncthreads();
    if (tid < DLQ) {
        const float* wr = gp_w + (size_t)tid * DMODEL;
        float s = 0.f;
        for (int j = 0; j < DMODEL; j += 4) {
            float4 w4 = *(const float4*)(wr + j);
            float4 x4 = *(const float4*)&xm[j];
            s += w4.x * x4.x + w4.y * x4.y + w4.z * x4.z + w4.w * x4.w;
        }
        float v = s + gp_b[tid];
        gc[tid] = v;
        ws[WS_GCTX + b * DLQ + tid] = v;
    }
    __syncthreads();
    if (tid < 128) {
        const float* wr = g1_w + (size_t)tid * DLQ;
        float s = 0.f;
        for (int j = 0; j < DLQ; j += 4) {
            float4 w4 = *(const float4*)(wr + j);
            float4 x4 = *(const float4*)&gc[j];
            s += w4.x * x4.x + w4.y * x4.y + w4.z * x4.z + w4.w * x4.w;
        }
        gb1[tid] = gelu_exact(s + g1_b[tid]);
    }
    __syncthreads();
    if (tid < NE) {
        const float* wr = g2_w + (size_t)tid * 128;
        float s = 0.f;
        for (int j = 0; j < 128; ++j) s += wr[j] * gb1[j];
        ws[WS_GB + b * NE + tid] = s + g2_b[tid];
    }
}

// K2: ef GEMM. 64x64 tile, K split over 2 blocks, BK=64, 3-term hi/lo bf16.
__global__ __launch_bounds__(256) void k_ef_mfma(float* __restrict__ ws) {
    __shared__ __attribute__((aligned(16))) unsigned short smem[16384];
    const unsigned short* AhP = (const unsigned short*)(ws + WS_AH);
    const unsigned short* AlP = (const unsigned short*)(ws + WS_AL);
    const unsigned short* BhP = (const unsigned short*)(ws + WS_BH);
    const unsigned short* BlP = (const unsigned short*)(ws + WS_BL);
    int tid = threadIdx.x;
    int mb = blockIdx.x;
    int nb = blockIdx.y;
    int kz = blockIdx.z;
    int w = tid >> 6, l = tid & 63;
    int wn = (w >> 1) * 32, wm = (w & 1) * 32;
    int stA = wn >> 4, stB = wm >> 4;
    f32x4 acc00 = {0.f, 0.f, 0.f, 0.f}, acc01 = acc00, acc10 = acc00, acc11 = acc00;

    for (int it = 0; it < 8; ++it) {
        int kb = kz * 8 + it;
        const char* srcs[4] = {
            (const char*)(AhP + (size_t)(nb * 16 + kb) * 4096),
            (const char*)(AlP + (size_t)(nb * 16 + kb) * 4096),
            (const char*)(BhP + (size_t)(mb * 16 + kb) * 4096),
            (const char*)(BlP + (size_t)(mb * 16 + kb) * 4096)};
#pragma unroll
        for (int p = 0; p < 4; ++p) {
#pragma unroll
            for (int h = 0; h < 2; ++h) {
                __builtin_amdgcn_global_load_lds(
                    (const __attribute__((address_space(1))) void*)(srcs[p] + h * 4096 + tid * 16),
                    (__attribute__((address_space(3))) void*)((char*)smem + p * 8192 + h * 4096 + tid * 16),
                    16, 0, 0);
            }
        }
        __syncthreads();
        const unsigned short* Ah = smem;
        const unsigned short* Al = smem + 4096;
        const unsigned short* Bh = smem + 8192;
        const unsigned short* Bl = smem + 12288;
#pragma unroll
        for (int ks = 0; ks < 2; ++ks) {
            short8 ah0 = *(const short8*)(Ah + (stA + 0) * 1024 + ks * 512 + l * 8);
            short8 ah1 = *(const short8*)(Ah + (stA + 1) * 1024 + ks * 512 + l * 8);
            short8 al0 = *(const short8*)(Al + (stA + 0) * 1024 + ks * 512 + l * 8);
            short8 al1 = *(const short8*)(Al + (stA + 1) * 1024 + ks * 512 + l * 8);
            short8 bh0 = *(const short8*)(Bh + (stB + 0) * 1024 + ks * 512 + l * 8);
            short8 bh1 = *(const short8*)(Bh + (stB + 1) * 1024 + ks * 512 + l * 8);
            short8 bl0 = *(const short8*)(Bl + (stB + 0) * 1024 + ks * 512 + l * 8);
            short8 bl1 = *(const short8*)(Bl + (stB + 1) * 1024 + ks * 512 + l * 8);
            acc00 = __builtin_amdgcn_mfma_f32_16x16x32_bf16(ah0, bh0, acc00, 0, 0, 0);
            acc00 = __builtin_amdgcn_mfma_f32_16x16x32_bf16(al0, bh0, acc00, 0, 0, 0);
            acc00 = __builtin_amdgcn_mfma_f32_16x16x32_bf16(ah0, bl0, acc00, 0, 0, 0);
            acc01 = __builtin_amdgcn_mfma_f32_16x16x32_bf16(ah0, bh1, acc01, 0, 0, 0);
            acc01 = __builtin_amdgcn_mfma_f32_16x16x32_bf16(al0, bh1, acc01, 0, 0, 0);
            acc01 = __builtin_amdgcn_mfma_f32_16x16x32_bf16(ah0, bl1, acc01, 0, 0, 0);
            acc10 = __builtin_amdgcn_mfma_f32_16x16x32_bf16(ah1, bh0, acc10, 0, 0, 0);
            acc10 = __builtin_amdgcn_mfma_f32_16x16x32_bf16(al1, bh0, acc10, 0, 0, 0);
            acc10 = __builtin_amdgcn_mfma_f32_16x16x32_bf16(ah1, bl0, acc10, 0, 0, 0);
            acc11 = __builtin_amdgcn_mfma_f32_16x16x32_bf16(ah1, bh1, acc11, 0, 0, 0);
            acc11 = __builtin_amdgcn_mfma_f32_16x16x32_bf16(al1, bh1, acc11, 0, 0, 0);
            acc11 = __builtin_amdgcn_mfma_f32_16x16x32_bf16(ah1, bl1, acc11, 0, 0, 0);
        }
        __syncthreads();
    }
    int cr = (l >> 4) * 4, cc = l & 15;
    int n0 = nb * 64, m0 = mb * 64;
    float* P = ws + (kz == 0 ? WS_EF : WS_P1);
#pragma unroll
    for (int r = 0; r < 4; ++r) {
        P[(size_t)(n0 + wn + cr + r) * DMODEL + (m0 + wm + cc)]           = acc00[r];
        P[(size_t)(n0 + wn + cr + r) * DMODEL + (m0 + wm + 16 + cc)]      = acc01[r];
        P[(size_t)(n0 + wn + 16 + cr + r) * DMODEL + (m0 + wm + cc)]      = acc10[r];
        P[(size_t)(n0 + wn + 16 + cr + r) * DMODEL + (m0 + wm + 16 + cc)] = acc11[r];
    }
}

// K2b: transpose w_up -> bf16 w_up^T (into dead AL region); blocks (0,1)/(0,2)
// build attn weight frag planes (into dead BH region). MUST run after k_ef_mfma.
__global__ __launch_bounds__(256) void k_prep_wup(const float* __restrict__ w_up,
                                                  const float* __restrict__ aiw,
                                                  const float* __restrict__ aow,
                                                  float* __restrict__ ws) {
    int e = blockIdx.x, ct = blockIdx.y, tid = threadIdx.x;
    __shared__ float tile[64][65];
#pragma unroll
    for (int jj = 0; jj < 16; ++jj) {
        int j = jj * 4 + (tid >> 6);
        tile[j][tid & 63] = w_up[((size_t)e * DLQ + j) * DMODEL + ct * 64 + (tid & 63)];
    }
    __syncthreads();
    int c = tid >> 2, j0 = (tid & 3) * 16;
    unsigned short* dst = (unsigned short*)(ws + WS_WUPT) +
                          (size_t)e * 65536 + (size_t)(ct * 64 + c) * 64 + j0;
#pragma unroll
    for (int q = 0; q < 4; ++q) {
        ushort4 o;
        o.x = f2bf(tile[j0 + q * 4 + 0][c]);
        o.y = f2bf(tile[j0 + q * 4 + 1][c]);
        o.z = f2bf(tile[j0 + q * 4 + 2][c]);
        o.w = f2bf(tile[j0 + q * 4 + 3][c]);
        *(ushort4*)(dst + q * 4) = o;
    }
    if (e == 0 && ct == 1) {
        unsigned short* fh = (unsigned short*)(ws + WS_AIWFH);
        unsigned short* fl = (unsigned short*)(ws + WS_AIWFL);
        for (int idx = tid; idx < 12 * 2 * 64; idx += 256) {
            int nt = idx >> 7, kf = (idx >> 6) & 1, l = idx & 63;
            int row = nt * 16 + (l & 15);
            int k = kf * 32 + ((l >> 4) << 3);
            const float* src = aiw + (size_t)row * DLQ + k;
            unsigned short h8[8], l8[8];
#pragma unroll
            for (int j = 0; j < 8; ++j) {
                h8[j] = f2bf(src[j]);
                l8[j] = f2bf(src[j] - bf2f(h8[j]));
            }
            size_t off = (size_t)(nt * 2 + kf) * 512 + l * 8;
            *(short8*)(fh + off) = *(short8*)h8;
            *(short8*)(fl + off) = *(short8*)l8;
        }
    }
    if (e == 0 && ct == 2) {
        unsigned short* gh = (unsigned short*)(ws + WS_AOWFH);
        unsigned short* gl = (unsigned short*)(ws + WS_AOWFL);
        for (int idx = tid; idx < 4 * 2 * 64; idx += 256) {
            int nt = idx >> 7, kf = (idx >> 6) & 1, l = idx & 63;
            int row = nt * 16 + (l & 15);
            int k = kf * 32 + ((l >> 4) << 3);
            const float* src = aow + (size_t)row * DLQ + k;
            unsigned short h8[8], l8[8];
#pragma unroll
            for (int j = 0; j < 8; ++j) {
                h8[j] = f2bf(src[j]);
                l8[j] = f2bf(src[j] - bf2f(h8[j]));
            }
            size_t off = (size_t)(nt * 2 + kf) * 512 + l * 8;
            *(short8*)(gh + off) = *(short8*)h8;
            *(short8*)(gl + off) = *(short8*)l8;
        }
    }
}

// K3: one token per block (2 waves). MFMA qkv/attn_out, DPP reduces, ACT
// epilogue. NO global atomics: lane 0 stores one packed ti int per token.
__global__ __launch_bounds__(128) void k_attn2(const float* __restrict__ pos_embed,
                                               const float* __restrict__ attn_in_b,
                                               const float* __restrict__ attn_out_b,
                                               const float* __restrict__ ln_w,
                                               const float* __restrict__ ln_b,
                                               const float* __restrict__ ls_w,
                                               const float* __restrict__ ls_b,
                                               float* __restrict__ ws) {
    int n = blockIdx.x;
    int w = threadIdx.x >> 6;
    int l = threadIdx.x & 63;
    int b = n >> 8;

    __shared__ float qkv[SEQL * 200];
    __shared__ __attribute__((aligned(16))) char ubuf[8192];   // sH/sL then ao
    __shared__ __attribute__((aligned(16))) unsigned short ctxH[1024];
    __shared__ __attribute__((aligned(16))) unsigned short ctxL[1024];
    __shared__ float lgv_sh[NE];
    unsigned short* sH = (unsigned short*)ubuf;
    unsigned short* sL = (unsigned short*)(ubuf + 4096);
    float* ao = (float*)ubuf;

    // Phase 1: seq = (P0+P1)[n] + pos; column l in regs; hi/lo frag LDS
    float seqc[SEQL];
    {
        const float* efp0 = ws + WS_EF + (size_t)n * DMODEL;
        const float* efp1 = ws + WS_P1 + (size_t)n * DMODEL;
        float gcv = ws[WS_GCTX + b * DLQ + l];
#pragma unroll
        for (int i = 0; i < SEQL; ++i) {
            float s = (i == 0) ? gcv
                               : efp0[(i - 1) * DLQ + l] + efp1[(i - 1) * DLQ + l] +
                                 pos_embed[(i - 1) * DLQ + l];
            seqc[i] = s;
            int lo_r = w * 9, hi_r = w * 9 + 8;
            if (i >= lo_r && i <= hi_r && i < SEQL) {
                unsigned short hs = f2bf(s);
                unsigned short lsv = f2bf(s - bf2f(hs));
                int mt = i >> 4;
                int ls = (i & 15) + (((l >> 3) & 3) << 4);
                int kf = l >> 5;
                int j = l & 7;
                size_t off = (size_t)(mt * 2 + kf) * 512 + ls * 8 + j;
                sH[off] = hs;
                sL[off] = lsv;
            }
        }
    }
    __syncthreads();

    // Phase 2: qkv = seq @ aiw^T via MFMA (wave w: N-tiles w*6..w*6+5)
    {
        const unsigned short* fh = (const unsigned short*)(ws + WS_AIWFH);
        const unsigned short* fl = (const unsigned short*)(ws + WS_AIWFL);
        f32x4 acc[6][2];
#pragma unroll
        for (int t = 0; t < 6; ++t)
#pragma unroll
            for (int m = 0; m < 2; ++m) acc[t][m] = (f32x4){0.f, 0.f, 0.f, 0.f};
#pragma unroll
        for (int kf = 0; kf < 2; ++kf) {
            short8 ah0 = *(const short8*)(sH + (0 * 2 + kf) * 512 + l * 8);
            short8 ah1 = *(const short8*)(sH + (1 * 2 + kf) * 512 + l * 8);
            short8 al0 = *(const short8*)(sL + (0 * 2 + kf) * 512 + l * 8);
            short8 al1 = *(const short8*)(sL + (1 * 2 + kf) * 512 + l * 8);
#pragma unroll
            for (int t = 0; t < 6; ++t) {
                int nt = w * 6 + t;
                short8 bh = *(const short8*)(fh + (size_t)(nt * 2 + kf) * 512 + l * 8);
                short8 bl = *(const short8*)(fl + (size_t)(nt * 2 + kf) * 512 + l * 8);
                acc[t][0] = __builtin_amdgcn_mfma_f32_16x16x32_bf16(ah0, bh, acc[t][0], 0, 0, 0);
                acc[t][0] = __builtin_amdgcn_mfma_f32_16x16x32_bf16(al0, bh, acc[t][0], 0, 0, 0);
                acc[t][0] = __builtin_amdgcn_mfma_f32_16x16x32_bf16(ah0, bl, acc[t][0], 0, 0, 0);
                acc[t][1] = __builtin_amdgcn_mfma_f32_16x16x32_bf16(ah1, bh, acc[t][1], 0, 0, 0);
                acc[t][1] = __builtin_amdgcn_mfma_f32_16x16x32_bf16(al1, bh, acc[t][1], 0, 0, 0);
                acc[t][1] = __builtin_amdgcn_mfma_f32_16x16x32_bf16(ah1, bl, acc[t][1], 0, 0, 0);
            }
        }
#pragma unroll
        for (int t = 0; t < 6; ++t) {
            int col = (w * 6 + t) * 16 + (l & 15);
            float bias = attn_in_b[col];
#pragma unroll
            for (int r = 0; r < 4; ++r) {
                int row = (l >> 4) * 4 + r;
                qkv[row * 200 + col] = acc[t][0][r] + bias;
            }
            if ((l >> 4) == 0) qkv[16 * 200 + col] = acc[t][1][0] + bias;
        }
    }
    __syncthreads();

    // Phase 3: scores via DPP 16-lane reduce, lane-local softmax, ctx.
    {
        int g = l >> 4;
        float kc[SEQL], vc[SEQL];
#pragma unroll
        for (int j = 0; j < SEQL; ++j) {
            kc[j] = qkv[j * 200 + 64 + g * 16 + (l & 15)];
            vc[j] = qkv[j * 200 + 128 + l];
        }
        for (int i = w * 8 + 1; i <= w * 8 + 8; ++i) {
            float qi = qkv[i * 200 + g * 16 + (l & 15)];
            float sj[SEQL];
#pragma unroll
            for (int j = 0; j < SEQL; ++j) {
                sj[j] = rsum16(qi * kc[j]) * 0.25f;
            }
            float m = sj[0];
#pragma unroll
            for (int j = 1; j < SEQL; ++j) m = fmaxf(m, sj[j]);
            float ssum = 0.f;
#pragma unroll
            for (int j = 0; j < SEQL; ++j) { sj[j] = __expf(sj[j] - m); ssum += sj[j]; }
            float inv = 1.f / ssum;
            float c = 0.f;
#pragma unroll
            for (int j = 0; j < SEQL; ++j) c += sj[j] * vc[j];
            c *= inv;
            unsigned short ch = f2bf(c);
            unsigned short cl = f2bf(c - bf2f(ch));
            int ls = ((i - 1) & 15) + (((l >> 3) & 3) << 4);
            int kf = l >> 5;
            int j2 = l & 7;
            size_t off = (size_t)kf * 512 + ls * 8 + j2;
            ctxH[off] = ch;
            ctxL[off] = cl;
        }
    }
    __syncthreads();

    // Phase 4: attn_out = ctx @ aow^T via MFMA (ao overlays sH/sL region)
    {
        const unsigned short* gh = (const unsigned short*)(ws + WS_AOWFH);
        const unsigned short* gl = (const unsigned short*)(ws + WS_AOWFL);
        f32x4 acc[2];
        acc[0] = (f32x4){0.f, 0.f, 0.f, 0.f};
        acc[1] = acc[0];
#pragma unroll
        for (int kf = 0; kf < 2; ++kf) {
            short8 ah = *(const short8*)(ctxH + kf * 512 + l * 8);
            short8 al = *(const short8*)(ctxL + kf * 512 + l * 8);
#pragma unroll
            for (int t = 0; t < 2; ++t) {
                int nt = w * 2 + t;
                short8 bh = *(const short8*)(gh + (size_t)(nt * 2 + kf) * 512 + l * 8);
                short8 bl = *(const short8*)(gl + (size_t)(nt * 2 + kf) * 512 + l * 8);
                acc[t] = __builtin_amdgcn_mfma_f32_16x16x32_bf16(ah, bh, acc[t], 0, 0, 0);
                acc[t] = __builtin_amdgcn_mfma_f32_16x16x32_bf16(al, bh, acc[t], 0, 0, 0);
                acc[t] = __builtin_amdgcn_mfma_f32_16x16x32_bf16(ah, bl, acc[t], 0, 0, 0);
            }
        }
        __syncthreads();
#pragma unroll
        for (int t = 0; t < 2; ++t) {
            int col = (w * 2 + t) * 16 + (l & 15);
            float bias = attn_out_b[col];
#pragma unroll
            for (int r = 0; r < 4; ++r) {
                int row = (l >> 4) * 4 + r;
                ao[row * 72 + col] = acc[t][r] + bias;
            }
        }
    }
    __syncthreads();

    // Phase 5: residual + LN + logits (wave w: e = w*8..w*8+7)
    float rs[SEQL];
#pragma unroll
    for (int i = 1; i < SEQL; ++i) rs[i] = seqc[i] + ao[(i - 1) * 72 + l];

    float c1 = ln_w[l] * ls_w[l];
    float c1sum = rsum64(c1);
    float c0sum = rsum64(ln_b[l] * ls_w[l]);
    float lsb0 = ls_b[0];
#pragma unroll
    for (int ee = 0; ee < 8; ++ee) {
        int e = w * 8 + ee;
        float x = rs[e + 1];
        float s1 = rsum64(x);
        float s2 = rsum64(x * x);
        float s3 = rsum64(x * c1);
        float mu = s1 * (1.0f / DLQ);
        float var = s2 * (1.0f / DLQ) - mu * mu;
        float rstd = rsqrtf(var + 1e-5f);
        float lgv = rstd * (s3 - mu * c1sum) + c0sum + lsb0 + ws[WS_GB + b * NE + e];
        if (l == 0) lgv_sh[e] = lgv;
    }
    __syncthreads();

    // softmax + top2 (only wave 0 commits)
    if (w == 0) {
        float p[NE];
        float lgv[NE];
#pragma unroll
        for (int e = 0; e < NE; ++e) lgv[e] = lgv_sh[e];
        float m = lgv[0];
#pragma unroll
        for (int e = 1; e < NE; ++e) m = fmaxf(m, lgv[e]);
        float ssum = 0.f;
#pragma unroll
        for (int e = 0; e < NE; ++e) { p[e] = __expf(lgv[e] - m); ssum += p[e]; }
        float inv = 1.f / ssum;
#pragma unroll
        for (int e = 0; e < NE; ++e) p[e] *= inv;
        int t0 = 0; float b0 = p[0];
#pragma unroll
        for (int e = 1; e < NE; ++e) if (p[e] > b0) { b0 = p[e]; t0 = e; }
        int t1 = -1; float b1 = -1.f;
#pragma unroll
        for (int e = 0; e < NE; ++e) if (e != t0 && p[e] > b1) { b1 = p[e]; t1 = e; }

        float sw = b0 + b1;
        float tw0 = b0 / sw, tw1 = b1 / sw;
        // ACT epilogue: gelu(ef of selected experts) * weight, bf16
        unsigned short* actp = (unsigned short*)(ws + WS_ACT);
        float efv0 = ws[WS_EF + (size_t)n * DMODEL + t0 * DLQ + l] +
                     ws[WS_P1 + (size_t)n * DMODEL + t0 * DLQ + l];
        float efv1 = ws[WS_EF + (size_t)n * DMODEL + t1 * DLQ + l] +
                     ws[WS_P1 + (size_t)n * DMODEL + t1 * DLQ + l];
        actp[(size_t)(n * 2 + 0) * 64 + l] = f2bf(gelu_exact(efv0) * tw0);
        actp[(size_t)(n * 2 + 1) * 64 + l] = f2bf(gelu_exact(efv1) * tw1);
        if (l == 0) {
#pragma unroll
            for (int e = 0; e < NE; ++e) ws[WS_PR + (size_t)n * NE + e] = p[e];
            ((int*)(ws + WS_TI))[n] = t0 | (t1 << 8);
        }
    }
}

// K4: expert-major MoE GEMM. Block = (e, 64-col tile), 4 waves. Builds its
// token list locally from ti (ballot compaction, LDS atomics only), then
// MFMAs ACT rows against w_up^T, accumulating into out via atomicAdd
// (2 commutative adds per element onto memset-zeroed out).
__global__ __launch_bounds__(256) void k_moe_gemm(float* __restrict__ ws,
                                                  float* __restrict__ out) {
    int e = blockIdx.x, ct = blockIdx.y;
    int tid = threadIdx.x;
    int wv = tid >> 6, l = tid & 63;
    __shared__ int lst[2048];
    __shared__ int lcnt;
    if (tid == 0) lcnt = 0;
    __syncthreads();
    {
        const int* tip = (const int*)(ws + WS_TI);
#pragma unroll
        for (int c = 0; c < 4; ++c) {
            int tok = wv * 256 + c * 64 + l;
            int pk = tip[tok];
            bool m1 = ((pk >> 8) & 0xff) == e;
            bool m = ((pk & 0xff) == e) || m1;
            unsigned long long mask = __ballot(m);
            int base = 0;
            if (l == 0 && mask) base = atomicAdd(&lcnt, __popcll(mask));
            base = __shfl(base, 0);
            if (m) {
                int pos = base + __popcll(mask & ((1ull << l) - 1ull));
                lst[pos] = tok * 2 + (m1 ? 1 : 0);
            }
        }
    }
    __syncthreads();
    int cnt = lcnt;
    if (cnt == 0) return;

    const unsigned short* wupt = (const unsigned short*)(ws + WS_WUPT) + (size_t)e * 65536;
    const unsigned short* actp = (const unsigned short*)(ws + WS_ACT);
    int col = ct * 64 + wv * 16 + (l & 15);
    int kb = (l >> 4) * 8;
    short8 bf0 = *(const short8*)(wupt + (size_t)col * 64 + kb);
    short8 bf1 = *(const short8*)(wupt + (size_t)col * 64 + 32 + kb);
    int cr = (l >> 4) * 4;

    for (int mt = 0; mt < cnt; mt += 16) {
        int row = mt + (l & 15);
        short8 a0 = {0, 0, 0, 0, 0, 0, 0, 0};
        short8 a1 = {0, 0, 0, 0, 0, 0, 0, 0};
        if (row < cnt) {
            int pk = lst[row];
            a0 = *(const short8*)(actp + (size_t)pk * 64 + kb);
            a1 = *(const short8*)(actp + (size_t)pk * 64 + 32 + kb);
        }
        f32x4 acc = {0.f, 0.f, 0.f, 0.f};
        acc = __builtin_amdgcn_mfma_f32_16x16x32_bf16(a0, bf0, acc, 0, 0, 0);
        acc = __builtin_amdgcn_mfma_f32_16x16x32_bf16(a1, bf1, acc, 0, 0, 0);
#pragma unroll
        for (int r = 0; r < 4; ++r) {
            int rr = mt + cr + r;
            if (rr < cnt) {
                int pk = lst[rr];
                atomicAdd(&out[(size_t)(pk >> 1) * DMODEL + col], acc[r]);
            }
        }
    }
}

// K6: aux loss from probs + ti histogram (LDS atomics only)
__global__ __launch_bounds__(256) void k_aux(const float* __restrict__ ws, float* __restrict__ out) {
    int tid = threadIdx.x;
    __shared__ float wsum[4][NE];
    __shared__ int hist[NE];
    if (tid < NE) hist[tid] = 0;
    __syncthreads();
    {
        const int* tip = (const int*)(ws + WS_TI);
#pragma unroll
        for (int c = 0; c < 4; ++c) {
            int pk = tip[tid * 4 + c];
            atomicAdd(&hist[pk & 0xff], 1);
            atomicAdd(&hist[(pk >> 8) & 0xff], 1);
        }
    }
    float p[NE];
#pragma unroll
    for (int e = 0; e < NE; ++e) p[e] = 0.f;
    const float* pr = ws + WS_PR + (size_t)tid * 64;
#pragma unroll
    for (int r = 0; r < 4; ++r)
#pragma unroll
        for (int q = 0; q < 4; ++q) {
            float4 v = *(const float4*)(pr + r * 16 + q * 4);
            p[q * 4 + 0] += v.x; p[q * 4 + 1] += v.y;
            p[q * 4 + 2] += v.z; p[q * 4 + 3] += v.w;
        }
#pragma unroll
    for (int e = 0; e < NE; ++e) p[e] = rsum64(p[e]);
    int w = tid >> 6, l = tid & 63;
    if (l == 0) {
#pragma unroll
        for (int e = 0; e < NE; ++e) wsum[w][e] = p[e];
    }
    __syncthreads();
    if (tid == 0) {
        float s = 0.f;
#pragma unroll
        for (int e = 0; e < NE; ++e) {
            float sp = wsum[0][e] + wsum[1][e] + wsum[2][e] + wsum[3][e];
            s += sp * (float)hist[e];
        }
        out[(size_t)NTOK * DMODEL] = (float)NE * s / ((float)NTOK * (float)NTOK);
    }
}

extern "C" void kernel_launch(void* const* d_in, const int* in_sizes, int n_in,
                              void* d_out, int out_size, void* d_ws, size_t ws_size,
                              hipStream_t stream) {
    const float* x          = (const float*)d_in[0];
    const float* w_down     = (const float*)d_in[1];
    const float* pos_embed  = (const float*)d_in[2];
    const float* gp_w       = (const float*)d_in[3];
    const float* gp_b       = (const float*)d_in[4];
    const float* attn_in_w  = (const float*)d_in[5];
    const float* attn_in_b  = (const float*)d_in[6];
    const float* attn_out_w = (const float*)d_in[7];
    const float* attn_out_b = (const float*)d_in[8];
    const float* ln_w       = (const float*)d_in[9];
    const float* ln_b       = (const float*)d_in[10];
    const float* ls_w       = (const float*)d_in[11];
    const float* ls_b       = (const float*)d_in[12];
    const float* g1_w       = (const float*)d_in[13];
    const float* g1_b       = (const float*)d_in[14];
    const float* g2_w       = (const float*)d_in[15];
    const float* g2_b       = (const float*)d_in[16];
    const float* w_up       = (const float*)d_in[17];
    float* ws  = (float*)d_ws;
    float* out = (float*)d_out;

    hipMemsetAsync(out, 0, (size_t)out_size * sizeof(float), stream);
    k_prep<<<dim3(512, 2), 256, 0, stream>>>(x, w_down, ws);
    k_batch_partial<<<32, 256, 0, stream>>>(x, ws);
    k_global_ctx<<<NB, 256, 0, stream>>>(gp_w, gp_b, g1_w, g1_b, g2_w, g2_b, ws);
    k_ef_mfma<<<dim3(16, 16, 2), 256, 0, stream>>>(ws);
    k_prep_wup<<<dim3(16, 16), 256, 0, stream>>>(w_up, attn_in_w, attn_out_w, ws);
    k_attn2<<<NTOK, 128, 0, stream>>>(pos_embed, attn_in_b, attn_out_b,
                                      ln_w, ln_b, ls_w, ls_b, ws);
    k_moe_gemm<<<dim3(NE, 16), 256, 0, stream>>>(ws, out);
    k_aux<<<1, 256, 0, stream>>>(ws, out);
}